// Round 7
// baseline (351.174 us; speedup 1.0000x reference)
//
#include <hip/hip_runtime.h>
#include <hip/hip_bf16.h>

#define T_    16
#define C_    64
#define H_    48
#define W_    48
#define HW_   2304
#define THW_  36864
#define CTHW_ 2359296
#define H2_   24
#define W2_   24
#define SD_   576
#define RC_   4
#define SDT_  72    // bf16 LDS tile row stride in shorts (144 B, 16B-multiple)

typedef short short8 __attribute__((ext_vector_type(8)));
typedef short short4v __attribute__((ext_vector_type(4)));
typedef float f32x4 __attribute__((ext_vector_type(4)));

__device__ __forceinline__ float sigm(float v) { return 1.f / (1.f + __expf(-v)); }
__device__ __forceinline__ unsigned short f2bf(float v) {
    __hip_bfloat16 h = __float2bfloat16(v);
    union { __hip_bfloat16 h; unsigned short u; } cv; cv.h = h; return cv.u;
}
__device__ __forceinline__ float bf2f(unsigned short u) {
    return __uint_as_float((unsigned)u << 16);
}

// ---------------- k_pre: fused x2T GEMM + bf16 split of x + xd = w_down@x ----------------
__global__ __launch_bounds__(256) void k_pre(const float* __restrict__ x,
                                             const float* __restrict__ w,
                                             const float* __restrict__ w_down,
                                             float* __restrict__ x2T,
                                             unsigned short* __restrict__ xbh,
                                             unsigned short* __restrict__ xbl,
                                             float* __restrict__ xd) {
    int base = blockIdx.x * 64;
    __shared__ float wl[64 * 65];
    __shared__ float xt[4096];
    __shared__ float ld[64 * 65];
    __shared__ float wd[256];
    int tid = threadIdx.x;
    for (int i = tid; i < 4096; i += 256) wl[(i >> 6) * 65 + (i & 63)] = w[i];
    for (int i = tid; i < 4096; i += 256) {
        float v = x[(size_t)(i >> 6) * THW_ + base + (i & 63)];
        xt[i] = v;
        ld[(i >> 6) * 65 + (i & 63)] = v;
    }
    if (tid < 256) wd[tid] = w_down[tid];
    __syncthreads();
    {
        int o_grp = tid >> 4, u_grp = tid & 15;
        float acc[4][4] = {};
        const float4* xt4 = (const float4*)xt;
        for (int c = 0; c < 64; ++c) {
            float xa[4];
            *(float4*)xa = xt4[c * 16 + u_grp];
            #pragma unroll
            for (int i = 0; i < 4; ++i) {
                float wv = wl[(o_grp * 4 + i) * 65 + c];
                #pragma unroll
                for (int g = 0; g < 4; ++g) acc[i][g] += wv * xa[g];
            }
        }
        #pragma unroll
        for (int g = 0; g < 4; ++g) {
            float4 v = make_float4(acc[0][g], acc[1][g], acc[2][g], acc[3][g]);
            *(float4*)&x2T[(size_t)(base + u_grp * 4 + g) * 64 + o_grp * 4] = v;
        }
    }
    {
        int r = tid >> 6, u = tid & 63;
        float a = 0.f;
        #pragma unroll 8
        for (int c = 0; c < 64; ++c) a += wd[r * 64 + c] * xt[c * 64 + u];
        xd[(size_t)r * THW_ + base + u] = a;
    }
    for (int i = tid; i < 4096; i += 256) {
        int u = i >> 6, c = i & 63;
        float v = ld[c * 65 + u];
        unsigned short h = f2bf(v);
        xbh[(size_t)(base + u) * 64 + c] = h;
        xbl[(size_t)(base + u) * 64 + c] = f2bf(v - bf2f(h));
    }
}

// ---------------- k_off: COALESCED x-read via xbh/xbl ([thw][c] layout) ----------------
__global__ __launch_bounds__(256) void k_off(const unsigned short* __restrict__ xbh,
                                             const unsigned short* __restrict__ xbl,
                                             const float* __restrict__ x2T,
                                             const float* __restrict__ w_l,
                                             const float* __restrict__ b_l,
                                             const float* __restrict__ w_r,
                                             const float* __restrict__ b_r,
                                             float* __restrict__ off) {
    __shared__ float wlds[2304];
    int tid = threadIdx.x;
    for (int i = tid; i < 2304; i += 256) wlds[i] = (i < 1152) ? w_l[i] : w_r[i - 1152];
    __syncthreads();
    int wg = blockIdx.x * 4 + (tid >> 6);
    int lane = tid & 63;
    int j = wg % 24, i = (wg / 24) % 24, t = (wg / 576) % 16, side = wg / 9216;
    int ts = (side == 0) ? min(t + 1, T_ - 1) : max(t - 1, 0);
    const float* wp = wlds + side * 1152;
    const unsigned short* xhb = xbh + ((size_t)t * HW_) * 64 + lane;
    const unsigned short* xlb = xbl + ((size_t)t * HW_) * 64 + lane;
    const float* x2l = x2T + (size_t)ts * HW_ * 64 + lane;
    float a0 = 0.f, a1 = 0.f;
    for (int ki = 0; ki < 3; ++ki) {
        int hh = 2 * i - 1 + ki;
        if (hh < 0 || hh >= H_) continue;
        for (int kj = 0; kj < 3; ++kj) {
            int ww = 2 * j - 1 + kj;
            if (ww < 0 || ww >= W_) continue;
            int pos = hh * W_ + ww;
            float s = bf2f(xhb[(size_t)pos * 64]) + bf2f(xlb[(size_t)pos * 64])
                    + x2l[(size_t)pos * 64];
            int tap = ki * 3 + kj;
            a0 += s * wp[lane * 9 + tap];
            a1 += s * wp[576 + lane * 9 + tap];
        }
    }
    #pragma unroll
    for (int m = 32; m >= 1; m >>= 1) {
        a0 += __shfl_xor(a0, m);
        a1 += __shfl_xor(a1, m);
    }
    if (lane == 0) {
        const float* bb = (side == 0) ? b_l : b_r;
        int ob = (side * 16 + t) * 1152 + i * 24 + j;
        off[ob] = a0 + bb[0];
        off[ob + 576] = a1 + bb[1];
    }
}

// ---------------- k_gs (verbatim) ----------------
__global__ __launch_bounds__(256) void k_gs(const float* __restrict__ x2T,
                                            const float* __restrict__ off,
                                            unsigned short* __restrict__ pch,
                                            unsigned short* __restrict__ pcl) {
    int wg = blockIdx.x * 4 + (threadIdx.x >> 6);
    int lane = threadIdx.x & 63;
    int sd = wg % 576;
    int t = (wg / 576) % 16;
    int side = wg / 9216;
    int d = sd % W2_, s = sd / W2_;
    const float* offp = off + (side * 16 + t) * 1152;
    float v0 = 2.f * (float)d + offp[sd];
    float v1 = 2.f * (float)s + offp[576 + sd];
    float xf = 48.f * v0 / 23.f - 0.5f;
    float yf = 48.f * v1 / 23.f - 0.5f;
    float x0 = floorf(xf), y0 = floorf(yf);
    int ix0 = (int)x0, iy0 = (int)y0;
    float fx = xf - x0, fy = yf - y0;
    float w00 = (1.f - fx) * (1.f - fy), w10 = fx * (1.f - fy);
    float w01 = (1.f - fx) * fy,         w11 = fx * fy;
    bool vx0 = (ix0 >= 0 && ix0 < W_), vx1 = (ix0 + 1 >= 0 && ix0 + 1 < W_);
    bool vy0 = (iy0 >= 0 && iy0 < H_), vy1 = (iy0 + 1 >= 0 && iy0 + 1 < H_);
    int cx0 = min(max(ix0, 0), W_ - 1), cx1 = min(max(ix0 + 1, 0), W_ - 1);
    int cy0 = min(max(iy0, 0), H_ - 1), cy1 = min(max(iy0 + 1, 0), H_ - 1);
    float m00 = (vx0 && vy0) ? w00 : 0.f;
    float m10 = (vx1 && vy0) ? w10 : 0.f;
    float m01 = (vx0 && vy1) ? w01 : 0.f;
    float m11 = (vx1 && vy1) ? w11 : 0.f;
    int ts = (side == 0) ? min(t + 1, T_ - 1) : max(t - 1, 0);
    const float* img = x2T + (size_t)ts * HW_ * 64;
    float val = m00 * img[(size_t)(cy0 * W_ + cx0) * 64 + lane]
              + m10 * img[(size_t)(cy0 * W_ + cx1) * 64 + lane]
              + m01 * img[(size_t)(cy1 * W_ + cx0) * 64 + lane]
              + m11 * img[(size_t)(cy1 * W_ + cx1) * 64 + lane];
    size_t idx = ((size_t)(side * 16 + t) * 576 + sd) * 64 + lane;
    unsigned short h = f2bf(val);
    pch[idx] = h;
    pcl[idx] = f2bf(val - bf2f(h));
}

// ---------------- k_stats: NO LDS, NO barriers — B-frags direct from global (L2) -------
// Per-lane MFMA B-fragment = 16B-aligned global read pch[st][kt*64+tile*16+l15][quad*8].
// XCD chunk swizzle keeps each XCD's hot pch/pcl slices ~300KB (fits per-XCD L2).
__global__ __launch_bounds__(256) void k_stats(const unsigned short* __restrict__ xbh,
                                               const unsigned short* __restrict__ xbl,
                                               const unsigned short* __restrict__ pch,
                                               const unsigned short* __restrict__ pcl,
                                               float* __restrict__ stats) {
    int bid = ((blockIdx.x & 7) * 144) + (blockIdx.x >> 3);   // bijective (1152 % 8 == 0)
    int side = bid & 1;
    int tb = bid >> 1;
    int t = tb / 36, hwt = tb % 36;
    int base = t * HW_ + hwt * 64;
    int tid = threadIdx.x;
    int lane = tid & 63, wv = tid >> 6;
    int quad = lane >> 4, l15 = lane & 15;
    int m0 = wv * 16;
    const unsigned short* xrh = xbh + (size_t)(base + m0 + l15) * 64;
    const unsigned short* xrl = xbl + (size_t)(base + m0 + l15) * 64;
    short8 ah0 = *(const short8*)&xrh[quad * 8];
    short8 ah1 = *(const short8*)&xrh[32 + quad * 8];
    short8 al0 = *(const short8*)&xrl[quad * 8];
    short8 al1 = *(const short8*)&xrl[32 + quad * 8];
    const unsigned short* phb = pch + (size_t)(side * 16 + t) * 576 * 64;
    const unsigned short* plb = pcl + (size_t)(side * 16 + t) * 576 * 64;
    int foff = l15 * 64 + quad * 8;
    float sum[4] = {}, sq[4] = {};
    float mx[4] = {-1e30f, -1e30f, -1e30f, -1e30f};
    #pragma unroll 1
    for (int kt = 0; kt < 9; ++kt) {
        const unsigned short* ph = phb + (size_t)kt * 4096;
        const unsigned short* pl = plb + (size_t)kt * 4096;
        #pragma unroll
        for (int tile = 0; tile < 4; ++tile) {
            int fo = tile * 1024 + foff;
            short8 bh0 = *(const short8*)&ph[fo];
            short8 bh1 = *(const short8*)&ph[fo + 32];
            short8 bl0 = *(const short8*)&pl[fo];
            short8 bl1 = *(const short8*)&pl[fo + 32];
            f32x4 dacc = {0.f, 0.f, 0.f, 0.f};
            dacc = __builtin_amdgcn_mfma_f32_16x16x32_bf16(ah0, bh0, dacc, 0, 0, 0);
            dacc = __builtin_amdgcn_mfma_f32_16x16x32_bf16(ah1, bh1, dacc, 0, 0, 0);
            dacc = __builtin_amdgcn_mfma_f32_16x16x32_bf16(ah0, bl0, dacc, 0, 0, 0);
            dacc = __builtin_amdgcn_mfma_f32_16x16x32_bf16(ah1, bl1, dacc, 0, 0, 0);
            dacc = __builtin_amdgcn_mfma_f32_16x16x32_bf16(al0, bh0, dacc, 0, 0, 0);
            dacc = __builtin_amdgcn_mfma_f32_16x16x32_bf16(al1, bh1, dacc, 0, 0, 0);
            #pragma unroll
            for (int r = 0; r < 4; ++r) {
                float v = dacc[r];
                sum[r] += v; sq[r] += v * v; mx[r] = fmaxf(mx[r], v);
            }
        }
    }
    #pragma unroll
    for (int m = 1; m < 16; m <<= 1)
        #pragma unroll
        for (int r = 0; r < 4; ++r) {
            sum[r] += __shfl_xor(sum[r], m);
            sq[r]  += __shfl_xor(sq[r], m);
            mx[r]   = fmaxf(mx[r], __shfl_xor(mx[r], m));
        }
    if (l15 == 0) {
        #pragma unroll
        for (int r = 0; r < 4; ++r) {
            int thw = base + m0 + quad * 4 + r;
            stats[(side * 3 + 0) * THW_ + thw] = sum[r] * (1.f / 576.f);
            stats[(side * 3 + 1) * THW_ + thw] = mx[r];
            stats[(side * 3 + 2) * THW_ + thw] =
                (sq[r] - sum[r] * sum[r] * (1.f / 576.f)) * (1.f / 575.f);
        }
    }
}

// ---------------- k_aux: fused attn (0..287) + agg (288..863) + TR transpose (864..1151)
__global__ __launch_bounds__(256) void k_aux(const float* __restrict__ stats,
                      const float* __restrict__ ca_w1,
                      const float* __restrict__ ca_w2, float* __restrict__ yb,
                      const float* __restrict__ xd,
                      const float* __restrict__ w1, const float* __restrict__ b1,
                      const float* __restrict__ w2, const float* __restrict__ b2,
                      const float* __restrict__ w3, const float* __restrict__ b3,
                      const float* __restrict__ wts, float* __restrict__ agg0,
                      const unsigned short* __restrict__ pch,
                      unsigned short* __restrict__ partb) {
    __shared__ unsigned short ld[64 * 68];
    int blk = blockIdx.x;
    int tid = threadIdx.x;
    if (blk < (2 * THW_) / 256) {
        // ---- attn body ----
        int idx = blk * 256 + tid;
        int side = idx / THW_, thw = idx % THW_;
        int w = thw % W_, h = (thw / W_) % H_, t = thw / HW_;
        const float* avg = stats + (side * 3 + 0) * THW_ + t * HW_;
        const float* mxp = stats + (side * 3 + 1) * THW_ + t * HW_;
        const float* var = stats + (side * 3 + 2) * THW_ + t * HW_;
        float acc = 0.f;
        for (int ki = 0; ki < 3; ++ki) {
            int hh = h - 1 + ki;
            if (hh < 0 || hh >= H_) continue;
            for (int kj = 0; kj < 3; ++kj) {
                int ww = w - 1 + kj;
                if (ww < 0 || ww >= W_) continue;
                int p = hh * W_ + ww;
                int kk = ki * 3 + kj;
                acc += ca_w1[kk] * avg[p] + ca_w1[9 + kk] * mxp[p] + ca_w2[kk] * var[p];
            }
        }
        yb[idx] = sigm(acc);
    } else if (blk < (2 * THW_) / 256 + (RC_ * THW_) / 256) {
        // ---- agg body ----
        int idx = (blk - (2 * THW_) / 256) * 256 + tid;
        int w = idx % W_;
        int h = (idx / W_) % H_;
        int t = (idx / HW_) % T_;
        int r = idx / THW_;
        const float* xr = xd + r * THW_;
        const float* wk_arr[3] = {w1, w2, w3};
        const float* bs_arr[3] = {b1, b2, b3};
        float tot = 0.f;
        for (int m = 0; m < 3; ++m) {
            int dil = m + 1;
            float acc = bs_arr[m][r];
            const float* wk = wk_arr[m] + r * 81;
            for (int kt = 0; kt < 9; ++kt) {
                int tt = t - 4 + kt;
                if (tt < 0 || tt >= T_) continue;
                for (int kh = 0; kh < 3; ++kh) {
                    int hh = h + (kh - 1) * dil;
                    if (hh < 0 || hh >= H_) continue;
                    for (int kw = 0; kw < 3; ++kw) {
                        int wwp = w + (kw - 1) * dil;
                        if (wwp < 0 || wwp >= W_) continue;
                        acc += xr[tt * HW_ + hh * W_ + wwp] * wk[kt * 9 + kh * 3 + kw];
                    }
                }
            }
            tot += acc * wts[m];
        }
        agg0[idx] = tot;
    } else {
        // ---- tr body (was k_tr) ----
        int b2 = blk - ((2 * THW_) / 256 + (RC_ * THW_) / 256);
        int st = b2 / 9;
        int sdt = b2 % 9;
        const unsigned short* src = pch + ((size_t)st * 576 + sdt * 64) * 64;
        for (int i = tid; i < 4096; i += 256) ld[(i >> 6) * 68 + (i & 63)] = src[i];
        __syncthreads();
        unsigned short* dst = partb + (size_t)st * 64 * 576 + sdt * 64;
        for (int i = tid; i < 4096; i += 256) {
            int c = i >> 6, sdl = i & 63;
            dst[(size_t)c * 576 + sdl] = ld[sdl * 68 + c];
        }
    }
}

// ---------------- k_final: phase-A B-frags direct from global; LDS holds only wt -------
// LDS ops/wave/iter: 36 -> 12 (4 wt writes + 8 wt reads). Staging + its bank conflicts
// gone; VMEM path (8% busy) absorbs the frag traffic (L2-resident pch/pcl).
// Still 2 barriers/iter, both protecting only wt. XCD chunk swizzle for L2 locality.
__global__ __launch_bounds__(256) void k_final(const unsigned short* __restrict__ xbh,
                                               const unsigned short* __restrict__ xbl,
                                               const unsigned short* __restrict__ pch,
                                               const unsigned short* __restrict__ pcl,
                                               const unsigned short* __restrict__ partb,
                                               const float* __restrict__ yb,
                                               const float* __restrict__ weights2,
                                               const float* __restrict__ agg0,
                                               const float* __restrict__ w_back,
                                               float* __restrict__ out) {
    int bid = ((blockIdx.x & 7) * 144) + (blockIdx.x >> 3);   // bijective (1152 % 8 == 0)
    int side = bid & 1;
    int tb = bid >> 1;
    int t = tb / 36, hwt = tb % 36;
    int base = t * HW_ + hwt * 64;
    int st = side * 16 + t;
    __shared__ __attribute__((aligned(16))) unsigned short wt[64 * SDT_];
    int tid = threadIdx.x;
    int lane = tid & 63, wv = tid >> 6;
    int quad = lane >> 4, l15 = lane & 15;
    int m0 = wv * 16;
    const unsigned short* xrh = xbh + (size_t)(base + m0 + l15) * 64;
    const unsigned short* xrl = xbl + (size_t)(base + m0 + l15) * 64;
    short8 ah0 = *(const short8*)&xrh[quad * 8];
    short8 ah1 = *(const short8*)&xrh[32 + quad * 8];
    short8 al0 = *(const short8*)&xrl[quad * 8];
    short8 al1 = *(const short8*)&xrl[32 + quad * 8];
    // gate is uniform over r in the swapped layout: hw row = m0 + l15
    float yvs = yb[(size_t)side * THW_ + base + m0 + l15];
    const unsigned short* phb = pch + (size_t)st * 576 * 64;
    const unsigned short* plb = pcl + (size_t)st * 576 * 64;
    const unsigned short* pbb = partb + (size_t)st * 64 * 576 + (size_t)(m0 + l15) * 576;
    int foff = l15 * 64 + quad * 8;
    short8 pbn0 = *(const short8*)&pbb[quad * 8];
    short8 pbn1 = *(const short8*)&pbb[32 + quad * 8];
    f32x4 acc[4] = {};
    #pragma unroll 1
    for (int kt = 0; kt < 9; ++kt) {
        if (kt) __syncthreads();   // X: prev iter's phase-B wt reads complete
        const unsigned short* ph = phb + (size_t)kt * 4096;
        const unsigned short* pl = plb + (size_t)kt * 4096;
        // phase A: aff tiles -> sigmoid weights (swapped operands: D[m=sd][n=hw])
        #pragma unroll
        for (int tile = 0; tile < 4; ++tile) {
            int fo = tile * 1024 + foff;
            short8 bh0 = *(const short8*)&ph[fo];
            short8 bh1 = *(const short8*)&ph[fo + 32];
            short8 bl0 = *(const short8*)&pl[fo];
            short8 bl1 = *(const short8*)&pl[fo + 32];
            f32x4 dacc = {0.f, 0.f, 0.f, 0.f};
            dacc = __builtin_amdgcn_mfma_f32_16x16x32_bf16(bh0, ah0, dacc, 0, 0, 0);
            dacc = __builtin_amdgcn_mfma_f32_16x16x32_bf16(bh1, ah1, dacc, 0, 0, 0);
            dacc = __builtin_amdgcn_mfma_f32_16x16x32_bf16(bl0, ah0, dacc, 0, 0, 0);
            dacc = __builtin_amdgcn_mfma_f32_16x16x32_bf16(bl1, ah1, dacc, 0, 0, 0);
            dacc = __builtin_amdgcn_mfma_f32_16x16x32_bf16(bh0, al0, dacc, 0, 0, 0);
            dacc = __builtin_amdgcn_mfma_f32_16x16x32_bf16(bh1, al1, dacc, 0, 0, 0);
            // dacc[r] = aff at (sd = kt*64 + tile*16 + quad*4 + r, hw = m0 + l15)
            short4v wq;
            #pragma unroll
            for (int r = 0; r < 4; ++r)
                wq[r] = (short)f2bf(sigm(dacc[r] * yvs) - 0.5f);
            *(short4v*)&wt[(m0 + l15) * SDT_ + tile * 16 + quad * 4] = wq;
        }
        __syncthreads();   // Y: wt visible
        short8 pA0 = pbn0, pA1 = pbn1;
        if (kt < 8) {
            const unsigned short* pbr = pbb + (kt + 1) * 64;
            pbn0 = *(const short8*)&pbr[quad * 8];
            pbn1 = *(const short8*)&pbr[32 + quad * 8];
        }
        // phase B: P (prefetched A-frag) x wt^T
        #pragma unroll
        for (int tile = 0; tile < 4; ++tile) {
            short8 wb0 = *(const short8*)&wt[(tile * 16 + l15) * SDT_ + quad * 8];
            short8 wb1 = *(const short8*)&wt[(tile * 16 + l15) * SDT_ + 32 + quad * 8];
            acc[tile] = __builtin_amdgcn_mfma_f32_16x16x32_bf16(pA0, wb0, acc[tile], 0, 0, 0);
            acc[tile] = __builtin_amdgcn_mfma_f32_16x16x32_bf16(pA1, wb1, acc[tile], 0, 0, 0);
        }
    }
    float w2s = weights2[side];
    #pragma unroll
    for (int tile = 0; tile < 4; ++tile) {
        int thw = base + tile * 16 + l15;
        #pragma unroll
        for (int r = 0; r < 4; ++r) {
            int c = m0 + quad * 4 + r;
            float a = 0.f;
            #pragma unroll
            for (int rr = 0; rr < RC_; ++rr) a += w_back[c * RC_ + rr] * agg0[rr * THW_ + thw];
            atomicAdd(&out[(size_t)c * THW_ + thw],
                      acc[tile][r] * w2s * (sigm(a) - 0.5f));
        }
    }
}

extern "C" void kernel_launch(void* const* d_in, const int* in_sizes, int n_in,
                              void* d_out, int out_size, void* d_ws, size_t ws_size,
                              hipStream_t stream) {
    const float* x       = (const float*)d_in[0];
    const float* w_dc2   = (const float*)d_in[1];
    const float* w_ofs_l = (const float*)d_in[2];
    const float* b_ofs_l = (const float*)d_in[3];
    const float* w_ofs_r = (const float*)d_in[4];
    const float* b_ofs_r = (const float*)d_in[5];
    const float* ca_w1   = (const float*)d_in[6];
    const float* ca_w2   = (const float*)d_in[7];
    const float* w_down  = (const float*)d_in[8];
    const float* sa1_w   = (const float*)d_in[9];
    const float* sa1_b   = (const float*)d_in[10];
    const float* sa2_w   = (const float*)d_in[11];
    const float* sa2_b   = (const float*)d_in[12];
    const float* sa3_w   = (const float*)d_in[13];
    const float* sa3_b   = (const float*)d_in[14];
    const float* weights = (const float*)d_in[15];
    const float* weights2= (const float*)d_in[16];
    const float* w_back  = (const float*)d_in[17];
    float* out = (float*)d_out;

    // workspace ~24.3 MB (identical layout to previous rounds)
    float* ws    = (float*)d_ws;
    float* x2T   = ws;                               // CTHW_ f32
    float* stats = x2T;                              // overlay: 221,184 f32
    float* yb    = stats + 2 * 3 * THW_;             // 73,728
    float* agg0  = yb + 2 * THW_;                    // 147,456
    unsigned short* partb = (unsigned short*)(agg0 + RC_ * THW_);  // 1,179,648 u16
    float* off   = ws + CTHW_;                       // 36,864 f32
    unsigned short* xbh = (unsigned short*)(off + 2 * T_ * 2 * SD_);  // CTHW_ u16
    unsigned short* xbl = xbh + CTHW_;                                // CTHW_ u16
    unsigned short* pch = xbl + CTHW_;               // 1,179,648 u16
    unsigned short* pcl = pch + 2 * 16 * 576 * 64;   // 1,179,648 u16
    float* xd    = (float*)(pcl + 2 * 16 * 576 * 64); // 147,456 f32

    k_pre<<<THW_ / 64, 256, 0, stream>>>(x, w_dc2, w_down, x2T, xbh, xbl, xd);
    k_off<<<(2 * 16 * 576) / 4, 256, 0, stream>>>(xbh, xbl, x2T, w_ofs_l, b_ofs_l,
                                                  w_ofs_r, b_ofs_r, off);
    k_gs<<<(2 * 16 * 576) / 4, 256, 0, stream>>>(x2T, off, pch, pcl);
    k_stats<<<2 * 16 * 36, 256, 0, stream>>>(xbh, xbl, pch, pcl, stats);
    k_aux<<<(2 * THW_) / 256 + (RC_ * THW_) / 256 + 32 * 9, 256, 0, stream>>>(
        stats, ca_w1, ca_w2, yb, xd, sa1_w, sa1_b, sa2_w, sa2_b,
        sa3_w, sa3_b, weights, agg0, pch, partb);
    k_final<<<2 * 16 * 36, 256, 0, stream>>>(xbh, xbl, pch, pcl, partb, yb, weights2,
                                             agg0, w_back, out);
}

// Round 8
// 287.172 us; speedup vs baseline: 1.2229x; 1.2229x over previous
//
#include <hip/hip_runtime.h>
#include <hip/hip_bf16.h>

#define T_    16
#define C_    64
#define H_    48
#define W_    48
#define HW_   2304
#define THW_  36864
#define CTHW_ 2359296
#define H2_   24
#define W2_   24
#define SD_   576
#define RC_   4
#define SDT_  72    // bf16 LDS tile row stride in shorts (144 B, 16B-multiple)

typedef short short8 __attribute__((ext_vector_type(8)));
typedef short short4v __attribute__((ext_vector_type(4)));
typedef float f32x4 __attribute__((ext_vector_type(4)));

__device__ __forceinline__ float sigm(float v) { return 1.f / (1.f + __expf(-v)); }
__device__ __forceinline__ unsigned short f2bf(float v) {
    __hip_bfloat16 h = __float2bfloat16(v);
    union { __hip_bfloat16 h; unsigned short u; } cv; cv.h = h; return cv.u;
}
__device__ __forceinline__ float bf2f(unsigned short u) {
    return __uint_as_float((unsigned)u << 16);
}

// ---------------- k_pre: fused x2T GEMM + bf16 split of x + xd = w_down@x ----------------
__global__ __launch_bounds__(256) void k_pre(const float* __restrict__ x,
                                             const float* __restrict__ w,
                                             const float* __restrict__ w_down,
                                             float* __restrict__ x2T,
                                             unsigned short* __restrict__ xbh,
                                             unsigned short* __restrict__ xbl,
                                             float* __restrict__ xd) {
    int base = blockIdx.x * 64;
    __shared__ float wl[64 * 65];
    __shared__ float xt[4096];
    __shared__ float ld[64 * 65];
    __shared__ float wd[256];
    int tid = threadIdx.x;
    for (int i = tid; i < 4096; i += 256) wl[(i >> 6) * 65 + (i & 63)] = w[i];
    for (int i = tid; i < 4096; i += 256) {
        float v = x[(size_t)(i >> 6) * THW_ + base + (i & 63)];
        xt[i] = v;
        ld[(i >> 6) * 65 + (i & 63)] = v;
    }
    if (tid < 256) wd[tid] = w_down[tid];
    __syncthreads();
    {
        int o_grp = tid >> 4, u_grp = tid & 15;
        float acc[4][4] = {};
        const float4* xt4 = (const float4*)xt;
        for (int c = 0; c < 64; ++c) {
            float xa[4];
            *(float4*)xa = xt4[c * 16 + u_grp];
            #pragma unroll
            for (int i = 0; i < 4; ++i) {
                float wv = wl[(o_grp * 4 + i) * 65 + c];
                #pragma unroll
                for (int g = 0; g < 4; ++g) acc[i][g] += wv * xa[g];
            }
        }
        #pragma unroll
        for (int g = 0; g < 4; ++g) {
            float4 v = make_float4(acc[0][g], acc[1][g], acc[2][g], acc[3][g]);
            *(float4*)&x2T[(size_t)(base + u_grp * 4 + g) * 64 + o_grp * 4] = v;
        }
    }
    {
        int r = tid >> 6, u = tid & 63;
        float a = 0.f;
        #pragma unroll 8
        for (int c = 0; c < 64; ++c) a += wd[r * 64 + c] * xt[c * 64 + u];
        xd[(size_t)r * THW_ + base + u] = a;
    }
    for (int i = tid; i < 4096; i += 256) {
        int u = i >> 6, c = i & 63;
        float v = ld[c * 65 + u];
        unsigned short h = f2bf(v);
        xbh[(size_t)(base + u) * 64 + c] = h;
        xbl[(size_t)(base + u) * 64 + c] = f2bf(v - bf2f(h));
    }
}

// ---------------- k_off: COALESCED x-read via xbh/xbl ([thw][c] layout) ----------------
__global__ __launch_bounds__(256) void k_off(const unsigned short* __restrict__ xbh,
                                             const unsigned short* __restrict__ xbl,
                                             const float* __restrict__ x2T,
                                             const float* __restrict__ w_l,
                                             const float* __restrict__ b_l,
                                             const float* __restrict__ w_r,
                                             const float* __restrict__ b_r,
                                             float* __restrict__ off) {
    __shared__ float wlds[2304];
    int tid = threadIdx.x;
    for (int i = tid; i < 2304; i += 256) wlds[i] = (i < 1152) ? w_l[i] : w_r[i - 1152];
    __syncthreads();
    int wg = blockIdx.x * 4 + (tid >> 6);
    int lane = tid & 63;
    int j = wg % 24, i = (wg / 24) % 24, t = (wg / 576) % 16, side = wg / 9216;
    int ts = (side == 0) ? min(t + 1, T_ - 1) : max(t - 1, 0);
    const float* wp = wlds + side * 1152;
    const unsigned short* xhb = xbh + ((size_t)t * HW_) * 64 + lane;
    const unsigned short* xlb = xbl + ((size_t)t * HW_) * 64 + lane;
    const float* x2l = x2T + (size_t)ts * HW_ * 64 + lane;
    float a0 = 0.f, a1 = 0.f;
    for (int ki = 0; ki < 3; ++ki) {
        int hh = 2 * i - 1 + ki;
        if (hh < 0 || hh >= H_) continue;
        for (int kj = 0; kj < 3; ++kj) {
            int ww = 2 * j - 1 + kj;
            if (ww < 0 || ww >= W_) continue;
            int pos = hh * W_ + ww;
            float s = bf2f(xhb[(size_t)pos * 64]) + bf2f(xlb[(size_t)pos * 64])
                    + x2l[(size_t)pos * 64];
            int tap = ki * 3 + kj;
            a0 += s * wp[lane * 9 + tap];
            a1 += s * wp[576 + lane * 9 + tap];
        }
    }
    #pragma unroll
    for (int m = 32; m >= 1; m >>= 1) {
        a0 += __shfl_xor(a0, m);
        a1 += __shfl_xor(a1, m);
    }
    if (lane == 0) {
        const float* bb = (side == 0) ? b_l : b_r;
        int ob = (side * 16 + t) * 1152 + i * 24 + j;
        off[ob] = a0 + bb[0];
        off[ob + 576] = a1 + bb[1];
    }
}

// ---------------- k_gs (verbatim) ----------------
__global__ __launch_bounds__(256) void k_gs(const float* __restrict__ x2T,
                                            const float* __restrict__ off,
                                            unsigned short* __restrict__ pch,
                                            unsigned short* __restrict__ pcl) {
    int wg = blockIdx.x * 4 + (threadIdx.x >> 6);
    int lane = threadIdx.x & 63;
    int sd = wg % 576;
    int t = (wg / 576) % 16;
    int side = wg / 9216;
    int d = sd % W2_, s = sd / W2_;
    const float* offp = off + (side * 16 + t) * 1152;
    float v0 = 2.f * (float)d + offp[sd];
    float v1 = 2.f * (float)s + offp[576 + sd];
    float xf = 48.f * v0 / 23.f - 0.5f;
    float yf = 48.f * v1 / 23.f - 0.5f;
    float x0 = floorf(xf), y0 = floorf(yf);
    int ix0 = (int)x0, iy0 = (int)y0;
    float fx = xf - x0, fy = yf - y0;
    float w00 = (1.f - fx) * (1.f - fy), w10 = fx * (1.f - fy);
    float w01 = (1.f - fx) * fy,         w11 = fx * fy;
    bool vx0 = (ix0 >= 0 && ix0 < W_), vx1 = (ix0 + 1 >= 0 && ix0 + 1 < W_);
    bool vy0 = (iy0 >= 0 && iy0 < H_), vy1 = (iy0 + 1 >= 0 && iy0 + 1 < H_);
    int cx0 = min(max(ix0, 0), W_ - 1), cx1 = min(max(ix0 + 1, 0), W_ - 1);
    int cy0 = min(max(iy0, 0), H_ - 1), cy1 = min(max(iy0 + 1, 0), H_ - 1);
    float m00 = (vx0 && vy0) ? w00 : 0.f;
    float m10 = (vx1 && vy0) ? w10 : 0.f;
    float m01 = (vx0 && vy1) ? w01 : 0.f;
    float m11 = (vx1 && vy1) ? w11 : 0.f;
    int ts = (side == 0) ? min(t + 1, T_ - 1) : max(t - 1, 0);
    const float* img = x2T + (size_t)ts * HW_ * 64;
    float val = m00 * img[(size_t)(cy0 * W_ + cx0) * 64 + lane]
              + m10 * img[(size_t)(cy0 * W_ + cx1) * 64 + lane]
              + m01 * img[(size_t)(cy1 * W_ + cx0) * 64 + lane]
              + m11 * img[(size_t)(cy1 * W_ + cx1) * 64 + lane];
    size_t idx = ((size_t)(side * 16 + t) * 576 + sd) * 64 + lane;
    unsigned short h = f2bf(val);
    pch[idx] = h;
    pcl[idx] = f2bf(val - bf2f(h));
}

// ---------------- k_stats: REVERTED to proven R5/R6 single-buffer LDS version ----------
__global__ __launch_bounds__(256) void k_stats(const unsigned short* __restrict__ xbh,
                                               const unsigned short* __restrict__ xbl,
                                               const unsigned short* __restrict__ pch,
                                               const unsigned short* __restrict__ pcl,
                                               float* __restrict__ stats) {
    int bid = blockIdx.x;
    int side = bid & 1;
    int tb = bid >> 1;
    int t = tb / 36, hwt = tb % 36;
    int base = t * HW_ + hwt * 64;
    __shared__ __attribute__((aligned(16))) unsigned short psh[64 * SDT_];
    __shared__ __attribute__((aligned(16))) unsigned short psl[64 * SDT_];
    int tid = threadIdx.x;
    int lane = tid & 63, wv = tid >> 6;
    int quad = lane >> 4, l15 = lane & 15;
    int m0 = wv * 16;
    const unsigned short* xrh = xbh + (size_t)(base + m0 + l15) * 64;
    const unsigned short* xrl = xbl + (size_t)(base + m0 + l15) * 64;
    short8 ah0 = *(const short8*)&xrh[quad * 8];
    short8 ah1 = *(const short8*)&xrh[32 + quad * 8];
    short8 al0 = *(const short8*)&xrl[quad * 8];
    short8 al1 = *(const short8*)&xrl[32 + quad * 8];
    int sH[4], sC[4];
    #pragma unroll
    for (int k = 0; k < 4; ++k) { int i = tid + k * 256; sH[k] = i >> 4; sC[k] = i & 15; }
    const unsigned short* phb = pch + (size_t)(side * 16 + t) * 576 * 64;
    const unsigned short* plb = pcl + (size_t)(side * 16 + t) * 576 * 64;
    uint2 pf_h[4], pf_l[4];
    #pragma unroll
    for (int k = 0; k < 4; ++k) {   // prefetch kt0
        pf_h[k] = *(const uint2*)&phb[(size_t)sH[k] * 64 + sC[k] * 4];
        pf_l[k] = *(const uint2*)&plb[(size_t)sH[k] * 64 + sC[k] * 4];
    }
    #pragma unroll
    for (int k = 0; k < 4; ++k) {   // stage kt0
        *(uint2*)&psh[sH[k] * SDT_ + sC[k] * 4] = pf_h[k];
        *(uint2*)&psl[sH[k] * SDT_ + sC[k] * 4] = pf_l[k];
    }
    #pragma unroll
    for (int k = 0; k < 4; ++k) {   // prefetch kt1
        pf_h[k] = *(const uint2*)&phb[4096 + (size_t)sH[k] * 64 + sC[k] * 4];
        pf_l[k] = *(const uint2*)&plb[4096 + (size_t)sH[k] * 64 + sC[k] * 4];
    }
    float sum[4] = {}, sq[4] = {};
    float mx[4] = {-1e30f, -1e30f, -1e30f, -1e30f};
    for (int kt = 0; kt < 9; ++kt) {
        __syncthreads();   // X: stage(kt) visible
        #pragma unroll
        for (int tile = 0; tile < 4; ++tile) {
            short8 bh0 = *(const short8*)&psh[(tile * 16 + l15) * SDT_ + quad * 8];
            short8 bh1 = *(const short8*)&psh[(tile * 16 + l15) * SDT_ + 32 + quad * 8];
            short8 bl0 = *(const short8*)&psl[(tile * 16 + l15) * SDT_ + quad * 8];
            short8 bl1 = *(const short8*)&psl[(tile * 16 + l15) * SDT_ + 32 + quad * 8];
            f32x4 dacc = {0.f, 0.f, 0.f, 0.f};
            dacc = __builtin_amdgcn_mfma_f32_16x16x32_bf16(ah0, bh0, dacc, 0, 0, 0);
            dacc = __builtin_amdgcn_mfma_f32_16x16x32_bf16(ah1, bh1, dacc, 0, 0, 0);
            dacc = __builtin_amdgcn_mfma_f32_16x16x32_bf16(ah0, bl0, dacc, 0, 0, 0);
            dacc = __builtin_amdgcn_mfma_f32_16x16x32_bf16(ah1, bl1, dacc, 0, 0, 0);
            dacc = __builtin_amdgcn_mfma_f32_16x16x32_bf16(al0, bh0, dacc, 0, 0, 0);
            dacc = __builtin_amdgcn_mfma_f32_16x16x32_bf16(al1, bh1, dacc, 0, 0, 0);
            #pragma unroll
            for (int r = 0; r < 4; ++r) {
                float v = dacc[r];
                sum[r] += v; sq[r] += v * v; mx[r] = fmaxf(mx[r], v);
            }
        }
        if (kt < 8) {
            __syncthreads();   // Y: stage reads done
            #pragma unroll
            for (int k = 0; k < 4; ++k) {
                *(uint2*)&psh[sH[k] * SDT_ + sC[k] * 4] = pf_h[k];
                *(uint2*)&psl[sH[k] * SDT_ + sC[k] * 4] = pf_l[k];
            }
            if (kt < 7) {
                const unsigned short* ph = phb + (size_t)(kt + 2) * 4096;
                const unsigned short* pl = plb + (size_t)(kt + 2) * 4096;
                #pragma unroll
                for (int k = 0; k < 4; ++k) {
                    pf_h[k] = *(const uint2*)&ph[(size_t)sH[k] * 64 + sC[k] * 4];
                    pf_l[k] = *(const uint2*)&pl[(size_t)sH[k] * 64 + sC[k] * 4];
                }
            }
        }
    }
    #pragma unroll
    for (int m = 1; m < 16; m <<= 1)
        #pragma unroll
        for (int r = 0; r < 4; ++r) {
            sum[r] += __shfl_xor(sum[r], m);
            sq[r]  += __shfl_xor(sq[r], m);
            mx[r]   = fmaxf(mx[r], __shfl_xor(mx[r], m));
        }
    if (l15 == 0) {
        #pragma unroll
        for (int r = 0; r < 4; ++r) {
            int thw = base + m0 + quad * 4 + r;
            stats[(side * 3 + 0) * THW_ + thw] = sum[r] * (1.f / 576.f);
            stats[(side * 3 + 1) * THW_ + thw] = mx[r];
            stats[(side * 3 + 2) * THW_ + thw] =
                (sq[r] - sum[r] * sum[r] * (1.f / 576.f)) * (1.f / 575.f);
        }
    }
}

// ---------------- k_aux: fused attn (0..287) + agg (288..863) + TR transpose (864..1151)
__global__ __launch_bounds__(256) void k_aux(const float* __restrict__ stats,
                      const float* __restrict__ ca_w1,
                      const float* __restrict__ ca_w2, float* __restrict__ yb,
                      const float* __restrict__ xd,
                      const float* __restrict__ w1, const float* __restrict__ b1,
                      const float* __restrict__ w2, const float* __restrict__ b2,
                      const float* __restrict__ w3, const float* __restrict__ b3,
                      const float* __restrict__ wts, float* __restrict__ agg0,
                      const unsigned short* __restrict__ pch,
                      unsigned short* __restrict__ partb) {
    __shared__ unsigned short ld[64 * 68];
    int blk = blockIdx.x;
    int tid = threadIdx.x;
    if (blk < (2 * THW_) / 256) {
        // ---- attn body ----
        int idx = blk * 256 + tid;
        int side = idx / THW_, thw = idx % THW_;
        int w = thw % W_, h = (thw / W_) % H_, t = thw / HW_;
        const float* avg = stats + (side * 3 + 0) * THW_ + t * HW_;
        const float* mxp = stats + (side * 3 + 1) * THW_ + t * HW_;
        const float* var = stats + (side * 3 + 2) * THW_ + t * HW_;
        float acc = 0.f;
        for (int ki = 0; ki < 3; ++ki) {
            int hh = h - 1 + ki;
            if (hh < 0 || hh >= H_) continue;
            for (int kj = 0; kj < 3; ++kj) {
                int ww = w - 1 + kj;
                if (ww < 0 || ww >= W_) continue;
                int p = hh * W_ + ww;
                int kk = ki * 3 + kj;
                acc += ca_w1[kk] * avg[p] + ca_w1[9 + kk] * mxp[p] + ca_w2[kk] * var[p];
            }
        }
        yb[idx] = sigm(acc);
    } else if (blk < (2 * THW_) / 256 + (RC_ * THW_) / 256) {
        // ---- agg body ----
        int idx = (blk - (2 * THW_) / 256) * 256 + tid;
        int w = idx % W_;
        int h = (idx / W_) % H_;
        int t = (idx / HW_) % T_;
        int r = idx / THW_;
        const float* xr = xd + r * THW_;
        const float* wk_arr[3] = {w1, w2, w3};
        const float* bs_arr[3] = {b1, b2, b3};
        float tot = 0.f;
        for (int m = 0; m < 3; ++m) {
            int dil = m + 1;
            float acc = bs_arr[m][r];
            const float* wk = wk_arr[m] + r * 81;
            for (int kt = 0; kt < 9; ++kt) {
                int tt = t - 4 + kt;
                if (tt < 0 || tt >= T_) continue;
                for (int kh = 0; kh < 3; ++kh) {
                    int hh = h + (kh - 1) * dil;
                    if (hh < 0 || hh >= H_) continue;
                    for (int kw = 0; kw < 3; ++kw) {
                        int wwp = w + (kw - 1) * dil;
                        if (wwp < 0 || wwp >= W_) continue;
                        acc += xr[tt * HW_ + hh * W_ + wwp] * wk[kt * 9 + kh * 3 + kw];
                    }
                }
            }
            tot += acc * wts[m];
        }
        agg0[idx] = tot;
    } else {
        // ---- tr body (was k_tr) ----
        int b2 = blk - ((2 * THW_) / 256 + (RC_ * THW_) / 256);
        int st = b2 / 9;
        int sdt = b2 % 9;
        const unsigned short* src = pch + ((size_t)st * 576 + sdt * 64) * 64;
        for (int i = tid; i < 4096; i += 256) ld[(i >> 6) * 68 + (i & 63)] = src[i];
        __syncthreads();
        unsigned short* dst = partb + (size_t)st * 64 * 576 + sdt * 64;
        for (int i = tid; i < 4096; i += 256) {
            int c = i >> 6, sdl = i & 63;
            dst[(size_t)c * 576 + sdl] = ld[sdl * 68 + c];
        }
    }
}

// ---------------- k_final: dbuf stage, 1 barrier/iter, wt in REGISTERS -----------------
// Phase A (swapped mfma) leaves lane with wt(sd=tile*16+quad*4+r, hw=m0+l15) — exactly
// the B-frag layout B[k][n] for a K=32 MFMA with two sd-16 tiles packed into the 8
// k-slots (k=q*8+j <-> sd=(j<4?tA:tB)*16+q*4+(j&3)). Phase B: mfma(partb_frag, wt_regs)
// -> D[m=c][n=hw]; wave owns hw-16 x all c. wt never touches LDS: -12 LDS ops/iter,
// -1 barrier/iter, -~2M conflict cycles (R7 isolated wt-only = 1.99M). partb A-frags:
// 16 x 8B loads/wave-iter, identical across the 4 waves -> L1-served (8KB/block-iter L2).
__global__ __launch_bounds__(256) void k_final(const unsigned short* __restrict__ xbh,
                                               const unsigned short* __restrict__ xbl,
                                               const unsigned short* __restrict__ pch,
                                               const unsigned short* __restrict__ pcl,
                                               const unsigned short* __restrict__ partb,
                                               const float* __restrict__ yb,
                                               const float* __restrict__ weights2,
                                               const float* __restrict__ agg0,
                                               const float* __restrict__ w_back,
                                               float* __restrict__ out) {
    int bid = blockIdx.x;
    int side = bid & 1;
    int tb = bid >> 1;
    int t = tb / 36, hwt = tb % 36;
    int base = t * HW_ + hwt * 64;
    int st = side * 16 + t;
    __shared__ __attribute__((aligned(16))) unsigned short pah[2][64 * SDT_];
    __shared__ __attribute__((aligned(16))) unsigned short pal[2][64 * SDT_];
    int tid = threadIdx.x;
    int lane = tid & 63, wv = tid >> 6;
    int quad = lane >> 4, l15 = lane & 15;
    int m0 = wv * 16;
    const unsigned short* xrh = xbh + (size_t)(base + m0 + l15) * 64;
    const unsigned short* xrl = xbl + (size_t)(base + m0 + l15) * 64;
    short8 ah0 = *(const short8*)&xrh[quad * 8];
    short8 ah1 = *(const short8*)&xrh[32 + quad * 8];
    short8 al0 = *(const short8*)&xrl[quad * 8];
    short8 al1 = *(const short8*)&xrl[32 + quad * 8];
    // gate uniform over r: hw row = m0 + l15
    float yvs = yb[(size_t)side * THW_ + base + m0 + l15];
    int sH[4], sC[4];
    #pragma unroll
    for (int k = 0; k < 4; ++k) { int i = tid + k * 256; sH[k] = i >> 4; sC[k] = i & 15; }
    const unsigned short* phb = pch + (size_t)st * 576 * 64;
    const unsigned short* plb = pcl + (size_t)st * 576 * 64;
    const unsigned short* pbs = partb + (size_t)st * 64 * 576;   // [c][sd]
    uint2 pf_h[4], pf_l[4];
    #pragma unroll
    for (int k = 0; k < 4; ++k) {   // prefetch stage kt0
        pf_h[k] = *(const uint2*)&phb[(size_t)sH[k] * 64 + sC[k] * 4];
        pf_l[k] = *(const uint2*)&plb[(size_t)sH[k] * 64 + sC[k] * 4];
    }
    f32x4 acc[4] = {};
    for (int kt = 0; kt < 9; ++kt) {
        int b = kt & 1;
        // write stage[b] (data kt) from prefetch regs
        #pragma unroll
        for (int k = 0; k < 4; ++k) {
            *(uint2*)&pah[b][sH[k] * SDT_ + sC[k] * 4] = pf_h[k];
            *(uint2*)&pal[b][sH[k] * SDT_ + sC[k] * 4] = pf_l[k];
        }
        if (kt < 8) {   // prefetch stage kt+1
            const unsigned short* ph = phb + (size_t)(kt + 1) * 4096;
            const unsigned short* pl = plb + (size_t)(kt + 1) * 4096;
            #pragma unroll
            for (int k = 0; k < 4; ++k) {
                pf_h[k] = *(const uint2*)&ph[(size_t)sH[k] * 64 + sC[k] * 4];
                pf_l[k] = *(const uint2*)&pl[(size_t)sH[k] * 64 + sC[k] * 4];
            }
        }
        __syncthreads();   // stage[b] visible (dbuf: prev reads of b were pre-prev-barrier)
        // phase-B A-frags for this kt: partb[c][kt*64 + tile*16 + quad*4 .. +4]
        short4v pa[4][4];
        #pragma unroll
        for (int ct = 0; ct < 4; ++ct) {
            const unsigned short* pr = pbs + (size_t)(ct * 16 + l15) * 576 + kt * 64 + quad * 4;
            pa[ct][0] = *(const short4v*)&pr[0];
            pa[ct][1] = *(const short4v*)&pr[16];
            pa[ct][2] = *(const short4v*)&pr[32];
            pa[ct][3] = *(const short4v*)&pr[48];
        }
        // phase A: aff -> sigmoid weights, kept in registers (swapped operands)
        short4v wt4[4];
        #pragma unroll
        for (int tile = 0; tile < 4; ++tile) {
            short8 bh0 = *(const short8*)&pah[b][(tile * 16 + l15) * SDT_ + quad * 8];
            short8 bh1 = *(const short8*)&pah[b][(tile * 16 + l15) * SDT_ + 32 + quad * 8];
            short8 bl0 = *(const short8*)&pal[b][(tile * 16 + l15) * SDT_ + quad * 8];
            short8 bl1 = *(const short8*)&pal[b][(tile * 16 + l15) * SDT_ + 32 + quad * 8];
            f32x4 dacc = {0.f, 0.f, 0.f, 0.f};
            dacc = __builtin_amdgcn_mfma_f32_16x16x32_bf16(bh0, ah0, dacc, 0, 0, 0);
            dacc = __builtin_amdgcn_mfma_f32_16x16x32_bf16(bh1, ah1, dacc, 0, 0, 0);
            dacc = __builtin_amdgcn_mfma_f32_16x16x32_bf16(bl0, ah0, dacc, 0, 0, 0);
            dacc = __builtin_amdgcn_mfma_f32_16x16x32_bf16(bl1, ah1, dacc, 0, 0, 0);
            dacc = __builtin_amdgcn_mfma_f32_16x16x32_bf16(bh0, al0, dacc, 0, 0, 0);
            dacc = __builtin_amdgcn_mfma_f32_16x16x32_bf16(bh1, al1, dacc, 0, 0, 0);
            // dacc[r] = aff at (sd = kt*64 + tile*16 + quad*4 + r, hw = m0 + l15)
            short4v wq;
            #pragma unroll
            for (int r = 0; r < 4; ++r)
                wq[r] = (short)f2bf(sigm(dacc[r] * yvs) - 0.5f);
            wt4[tile] = wq;
        }
        // phase B: no barrier — wt is wave-local. Pack tile pairs into K=32 fragments.
        short8 wf01 = __builtin_shufflevector(wt4[0], wt4[1], 0, 1, 2, 3, 4, 5, 6, 7);
        short8 wf23 = __builtin_shufflevector(wt4[2], wt4[3], 0, 1, 2, 3, 4, 5, 6, 7);
        #pragma unroll
        for (int ct = 0; ct < 4; ++ct) {
            short8 a01 = __builtin_shufflevector(pa[ct][0], pa[ct][1], 0, 1, 2, 3, 4, 5, 6, 7);
            short8 a23 = __builtin_shufflevector(pa[ct][2], pa[ct][3], 0, 1, 2, 3, 4, 5, 6, 7);
            acc[ct] = __builtin_amdgcn_mfma_f32_16x16x32_bf16(a01, wf01, acc[ct], 0, 0, 0);
            acc[ct] = __builtin_amdgcn_mfma_f32_16x16x32_bf16(a23, wf23, acc[ct], 0, 0, 0);
        }
    }
    // epilogue: acc[ct][r] = out-partial at (c = ct*16+quad*4+r, thw = base+m0+l15)
    float w2s = weights2[side];
    int thw = base + m0 + l15;
    float agv[RC_];
    #pragma unroll
    for (int rr = 0; rr < RC_; ++rr) agv[rr] = agg0[rr * THW_ + thw];
    #pragma unroll
    for (int ct = 0; ct < 4; ++ct) {
        #pragma unroll
        for (int r = 0; r < 4; ++r) {
            int c = ct * 16 + quad * 4 + r;
            float a = 0.f;
            #pragma unroll
            for (int rr = 0; rr < RC_; ++rr) a += w_back[c * RC_ + rr] * agv[rr];
            atomicAdd(&out[(size_t)c * THW_ + thw],
                      acc[ct][r] * w2s * (sigm(a) - 0.5f));
        }
    }
}

extern "C" void kernel_launch(void* const* d_in, const int* in_sizes, int n_in,
                              void* d_out, int out_size, void* d_ws, size_t ws_size,
                              hipStream_t stream) {
    const float* x       = (const float*)d_in[0];
    const float* w_dc2   = (const float*)d_in[1];
    const float* w_ofs_l = (const float*)d_in[2];
    const float* b_ofs_l = (const float*)d_in[3];
    const float* w_ofs_r = (const float*)d_in[4];
    const float* b_ofs_r = (const float*)d_in[5];
    const float* ca_w1   = (const float*)d_in[6];
    const float* ca_w2   = (const float*)d_in[7];
    const float* w_down  = (const float*)d_in[8];
    const float* sa1_w   = (const float*)d_in[9];
    const float* sa1_b   = (const float*)d_in[10];
    const float* sa2_w   = (const float*)d_in[11];
    const float* sa2_b   = (const float*)d_in[12];
    const float* sa3_w   = (const float*)d_in[13];
    const float* sa3_b   = (const float*)d_in[14];
    const float* weights = (const float*)d_in[15];
    const float* weights2= (const float*)d_in[16];
    const float* w_back  = (const float*)d_in[17];
    float* out = (float*)d_out;

    // workspace ~24.3 MB (identical layout to previous rounds)
    float* ws    = (float*)d_ws;
    float* x2T   = ws;                               // CTHW_ f32
    float* stats = x2T;                              // overlay: 221,184 f32
    float* yb    = stats + 2 * 3 * THW_;             // 73,728
    float* agg0  = yb + 2 * THW_;                    // 147,456
    unsigned short* partb = (unsigned short*)(agg0 + RC_ * THW_);  // 1,179,648 u16
    float* off   = ws + CTHW_;                       // 36,864 f32
    unsigned short* xbh = (unsigned short*)(off + 2 * T_ * 2 * SD_);  // CTHW_ u16
    unsigned short* xbl = xbh + CTHW_;                                // CTHW_ u16
    unsigned short* pch = xbl + CTHW_;               // 1,179,648 u16
    unsigned short* pcl = pch + 2 * 16 * 576 * 64;   // 1,179,648 u16
    float* xd    = (float*)(pcl + 2 * 16 * 576 * 64); // 147,456 f32

    k_pre<<<THW_ / 64, 256, 0, stream>>>(x, w_dc2, w_down, x2T, xbh, xbl, xd);
    k_off<<<(2 * 16 * 576) / 4, 256, 0, stream>>>(xbh, xbl, x2T, w_ofs_l, b_ofs_l,
                                                  w_ofs_r, b_ofs_r, off);
    k_gs<<<(2 * 16 * 576) / 4, 256, 0, stream>>>(x2T, off, pch, pcl);
    k_stats<<<2 * 16 * 36, 256, 0, stream>>>(xbh, xbl, pch, pcl, stats);
    k_aux<<<(2 * THW_) / 256 + (RC_ * THW_) / 256 + 32 * 9, 256, 0, stream>>>(
        stats, ca_w1, ca_w2, yb, xd, sa1_w, sa1_b, sa2_w, sa2_b,
        sa3_w, sa3_b, weights, agg0, pch, partb);
    k_final<<<2 * 16 * 36, 256, 0, stream>>>(xbh, xbl, pch, pcl, partb, yb, weights2,
                                             agg0, w_back, out);
}

// Round 9
// 240.221 us; speedup vs baseline: 1.4619x; 1.1954x over previous
//
#include <hip/hip_runtime.h>
#include <hip/hip_bf16.h>

#define T_    16
#define C_    64
#define H_    48
#define W_    48
#define HW_   2304
#define THW_  36864
#define CTHW_ 2359296
#define H2_   24
#define W2_   24
#define SD_   576
#define RC_   4
#define SDT_  72    // bf16 LDS tile row stride in shorts (144 B, 16B-multiple)

typedef short short8 __attribute__((ext_vector_type(8)));
typedef short short4v __attribute__((ext_vector_type(4)));
typedef float f32x4 __attribute__((ext_vector_type(4)));

__device__ __forceinline__ float sigm(float v) { return 1.f / (1.f + __expf(-v)); }
__device__ __forceinline__ unsigned short f2bf(float v) {
    __hip_bfloat16 h = __float2bfloat16(v);
    union { __hip_bfloat16 h; unsigned short u; } cv; cv.h = h; return cv.u;
}
__device__ __forceinline__ float bf2f(unsigned short u) {
    return __uint_as_float((unsigned)u << 16);
}
// Soft barrier: publish LDS ops (lgkmcnt) but leave private-register global loads
// (vmcnt) in flight across the barrier. __syncthreads would drain vmcnt(0) every
// iteration -> every wave stalls ~600-900cyc on prefetch loads not needed until the
// NEXT iteration (m97 barrier-drain mechanism; T4 counted-vmcnt fix). The compiler
// still inserts its own vmcnt(N) waits before the prefetch registers are consumed.
__device__ __forceinline__ void soft_barrier() {
    asm volatile("s_waitcnt lgkmcnt(0)" ::: "memory");
    __builtin_amdgcn_s_barrier();
}

// ---------------- k_pre: fused x2T GEMM + bf16 split of x + xd = w_down@x ----------------
__global__ __launch_bounds__(256) void k_pre(const float* __restrict__ x,
                                             const float* __restrict__ w,
                                             const float* __restrict__ w_down,
                                             float* __restrict__ x2T,
                                             unsigned short* __restrict__ xbh,
                                             unsigned short* __restrict__ xbl,
                                             float* __restrict__ xd) {
    int base = blockIdx.x * 64;
    __shared__ float wl[64 * 65];
    __shared__ float xt[4096];
    __shared__ float ld[64 * 65];
    __shared__ float wd[256];
    int tid = threadIdx.x;
    for (int i = tid; i < 4096; i += 256) wl[(i >> 6) * 65 + (i & 63)] = w[i];
    for (int i = tid; i < 4096; i += 256) {
        float v = x[(size_t)(i >> 6) * THW_ + base + (i & 63)];
        xt[i] = v;
        ld[(i >> 6) * 65 + (i & 63)] = v;
    }
    if (tid < 256) wd[tid] = w_down[tid];
    __syncthreads();
    {
        int o_grp = tid >> 4, u_grp = tid & 15;
        float acc[4][4] = {};
        const float4* xt4 = (const float4*)xt;
        for (int c = 0; c < 64; ++c) {
            float xa[4];
            *(float4*)xa = xt4[c * 16 + u_grp];
            #pragma unroll
            for (int i = 0; i < 4; ++i) {
                float wv = wl[(o_grp * 4 + i) * 65 + c];
                #pragma unroll
                for (int g = 0; g < 4; ++g) acc[i][g] += wv * xa[g];
            }
        }
        #pragma unroll
        for (int g = 0; g < 4; ++g) {
            float4 v = make_float4(acc[0][g], acc[1][g], acc[2][g], acc[3][g]);
            *(float4*)&x2T[(size_t)(base + u_grp * 4 + g) * 64 + o_grp * 4] = v;
        }
    }
    {
        int r = tid >> 6, u = tid & 63;
        float a = 0.f;
        #pragma unroll 8
        for (int c = 0; c < 64; ++c) a += wd[r * 64 + c] * xt[c * 64 + u];
        xd[(size_t)r * THW_ + base + u] = a;
    }
    for (int i = tid; i < 4096; i += 256) {
        int u = i >> 6, c = i & 63;
        float v = ld[c * 65 + u];
        unsigned short h = f2bf(v);
        xbh[(size_t)(base + u) * 64 + c] = h;
        xbl[(size_t)(base + u) * 64 + c] = f2bf(v - bf2f(h));
    }
}

// ---------------- k_off: COALESCED x-read via xbh/xbl ([thw][c] layout) ----------------
__global__ __launch_bounds__(256) void k_off(const unsigned short* __restrict__ xbh,
                                             const unsigned short* __restrict__ xbl,
                                             const float* __restrict__ x2T,
                                             const float* __restrict__ w_l,
                                             const float* __restrict__ b_l,
                                             const float* __restrict__ w_r,
                                             const float* __restrict__ b_r,
                                             float* __restrict__ off) {
    __shared__ float wlds[2304];
    int tid = threadIdx.x;
    for (int i = tid; i < 2304; i += 256) wlds[i] = (i < 1152) ? w_l[i] : w_r[i - 1152];
    __syncthreads();
    int wg = blockIdx.x * 4 + (tid >> 6);
    int lane = tid & 63;
    int j = wg % 24, i = (wg / 24) % 24, t = (wg / 576) % 16, side = wg / 9216;
    int ts = (side == 0) ? min(t + 1, T_ - 1) : max(t - 1, 0);
    const float* wp = wlds + side * 1152;
    const unsigned short* xhb = xbh + ((size_t)t * HW_) * 64 + lane;
    const unsigned short* xlb = xbl + ((size_t)t * HW_) * 64 + lane;
    const float* x2l = x2T + (size_t)ts * HW_ * 64 + lane;
    float a0 = 0.f, a1 = 0.f;
    for (int ki = 0; ki < 3; ++ki) {
        int hh = 2 * i - 1 + ki;
        if (hh < 0 || hh >= H_) continue;
        for (int kj = 0; kj < 3; ++kj) {
            int ww = 2 * j - 1 + kj;
            if (ww < 0 || ww >= W_) continue;
            int pos = hh * W_ + ww;
            float s = bf2f(xhb[(size_t)pos * 64]) + bf2f(xlb[(size_t)pos * 64])
                    + x2l[(size_t)pos * 64];
            int tap = ki * 3 + kj;
            a0 += s * wp[lane * 9 + tap];
            a1 += s * wp[576 + lane * 9 + tap];
        }
    }
    #pragma unroll
    for (int m = 32; m >= 1; m >>= 1) {
        a0 += __shfl_xor(a0, m);
        a1 += __shfl_xor(a1, m);
    }
    if (lane == 0) {
        const float* bb = (side == 0) ? b_l : b_r;
        int ob = (side * 16 + t) * 1152 + i * 24 + j;
        off[ob] = a0 + bb[0];
        off[ob + 576] = a1 + bb[1];
    }
}

// ---------------- k_gs (verbatim) ----------------
__global__ __launch_bounds__(256) void k_gs(const float* __restrict__ x2T,
                                            const float* __restrict__ off,
                                            unsigned short* __restrict__ pch,
                                            unsigned short* __restrict__ pcl) {
    int wg = blockIdx.x * 4 + (threadIdx.x >> 6);
    int lane = threadIdx.x & 63;
    int sd = wg % 576;
    int t = (wg / 576) % 16;
    int side = wg / 9216;
    int d = sd % W2_, s = sd / W2_;
    const float* offp = off + (side * 16 + t) * 1152;
    float v0 = 2.f * (float)d + offp[sd];
    float v1 = 2.f * (float)s + offp[576 + sd];
    float xf = 48.f * v0 / 23.f - 0.5f;
    float yf = 48.f * v1 / 23.f - 0.5f;
    float x0 = floorf(xf), y0 = floorf(yf);
    int ix0 = (int)x0, iy0 = (int)y0;
    float fx = xf - x0, fy = yf - y0;
    float w00 = (1.f - fx) * (1.f - fy), w10 = fx * (1.f - fy);
    float w01 = (1.f - fx) * fy,         w11 = fx * fy;
    bool vx0 = (ix0 >= 0 && ix0 < W_), vx1 = (ix0 + 1 >= 0 && ix0 + 1 < W_);
    bool vy0 = (iy0 >= 0 && iy0 < H_), vy1 = (iy0 + 1 >= 0 && iy0 + 1 < H_);
    int cx0 = min(max(ix0, 0), W_ - 1), cx1 = min(max(ix0 + 1, 0), W_ - 1);
    int cy0 = min(max(iy0, 0), H_ - 1), cy1 = min(max(iy0 + 1, 0), H_ - 1);
    float m00 = (vx0 && vy0) ? w00 : 0.f;
    float m10 = (vx1 && vy0) ? w10 : 0.f;
    float m01 = (vx0 && vy1) ? w01 : 0.f;
    float m11 = (vx1 && vy1) ? w11 : 0.f;
    int ts = (side == 0) ? min(t + 1, T_ - 1) : max(t - 1, 0);
    const float* img = x2T + (size_t)ts * HW_ * 64;
    float val = m00 * img[(size_t)(cy0 * W_ + cx0) * 64 + lane]
              + m10 * img[(size_t)(cy0 * W_ + cx1) * 64 + lane]
              + m01 * img[(size_t)(cy1 * W_ + cx0) * 64 + lane]
              + m11 * img[(size_t)(cy1 * W_ + cx1) * 64 + lane];
    size_t idx = ((size_t)(side * 16 + t) * 576 + sd) * 64 + lane;
    unsigned short h = f2bf(val);
    pch[idx] = h;
    pcl[idx] = f2bf(val - bf2f(h));
}

// ---------------- k_stats: side-split, dbuf stage, SOFT barrier (vmcnt stays in flight) -
__global__ __launch_bounds__(256) void k_stats(const unsigned short* __restrict__ xbh,
                                               const unsigned short* __restrict__ xbl,
                                               const unsigned short* __restrict__ pch,
                                               const unsigned short* __restrict__ pcl,
                                               float* __restrict__ stats) {
    int bid = blockIdx.x;
    int side = bid & 1;
    int tb = bid >> 1;
    int t = tb / 36, hwt = tb % 36;
    int base = t * HW_ + hwt * 64;
    __shared__ __attribute__((aligned(16))) unsigned short pah[2][64 * SDT_];
    __shared__ __attribute__((aligned(16))) unsigned short pal[2][64 * SDT_];
    int tid = threadIdx.x;
    int lane = tid & 63, wv = tid >> 6;
    int quad = lane >> 4, l15 = lane & 15;
    int m0 = wv * 16;
    const unsigned short* xrh = xbh + (size_t)(base + m0 + l15) * 64;
    const unsigned short* xrl = xbl + (size_t)(base + m0 + l15) * 64;
    short8 ah0 = *(const short8*)&xrh[quad * 8];
    short8 ah1 = *(const short8*)&xrh[32 + quad * 8];
    short8 al0 = *(const short8*)&xrl[quad * 8];
    short8 al1 = *(const short8*)&xrl[32 + quad * 8];
    int sH[4], sC[4];
    #pragma unroll
    for (int k = 0; k < 4; ++k) { int i = tid + k * 256; sH[k] = i >> 4; sC[k] = i & 15; }
    const unsigned short* phb = pch + (size_t)(side * 16 + t) * 576 * 64;
    const unsigned short* plb = pcl + (size_t)(side * 16 + t) * 576 * 64;
    uint2 pf_h[4], pf_l[4];
    #pragma unroll
    for (int k = 0; k < 4; ++k) {
        pf_h[k] = *(const uint2*)&phb[(size_t)sH[k] * 64 + sC[k] * 4];
        pf_l[k] = *(const uint2*)&plb[(size_t)sH[k] * 64 + sC[k] * 4];
    }
    float sum[4] = {}, sq[4] = {};
    float mx[4] = {-1e30f, -1e30f, -1e30f, -1e30f};
    for (int kt = 0; kt < 9; ++kt) {
        int b = kt & 1;
        #pragma unroll
        for (int k = 0; k < 4; ++k) {
            *(uint2*)&pah[b][sH[k] * SDT_ + sC[k] * 4] = pf_h[k];
            *(uint2*)&pal[b][sH[k] * SDT_ + sC[k] * 4] = pf_l[k];
        }
        if (kt < 8) {
            const unsigned short* ph = phb + (size_t)(kt + 1) * 4096;
            const unsigned short* pl = plb + (size_t)(kt + 1) * 4096;
            #pragma unroll
            for (int k = 0; k < 4; ++k) {
                pf_h[k] = *(const uint2*)&ph[(size_t)sH[k] * 64 + sC[k] * 4];
                pf_l[k] = *(const uint2*)&pl[(size_t)sH[k] * 64 + sC[k] * 4];
            }
        }
        soft_barrier();   // stage(kt) visible; prefetch loads stay in flight
        #pragma unroll
        for (int tile = 0; tile < 4; ++tile) {
            short8 bh0 = *(const short8*)&pah[b][(tile * 16 + l15) * SDT_ + quad * 8];
            short8 bh1 = *(const short8*)&pah[b][(tile * 16 + l15) * SDT_ + 32 + quad * 8];
            short8 bl0 = *(const short8*)&pal[b][(tile * 16 + l15) * SDT_ + quad * 8];
            short8 bl1 = *(const short8*)&pal[b][(tile * 16 + l15) * SDT_ + 32 + quad * 8];
            f32x4 dacc = {0.f, 0.f, 0.f, 0.f};
            dacc = __builtin_amdgcn_mfma_f32_16x16x32_bf16(ah0, bh0, dacc, 0, 0, 0);
            dacc = __builtin_amdgcn_mfma_f32_16x16x32_bf16(ah1, bh1, dacc, 0, 0, 0);
            dacc = __builtin_amdgcn_mfma_f32_16x16x32_bf16(ah0, bl0, dacc, 0, 0, 0);
            dacc = __builtin_amdgcn_mfma_f32_16x16x32_bf16(ah1, bl1, dacc, 0, 0, 0);
            dacc = __builtin_amdgcn_mfma_f32_16x16x32_bf16(al0, bh0, dacc, 0, 0, 0);
            dacc = __builtin_amdgcn_mfma_f32_16x16x32_bf16(al1, bh1, dacc, 0, 0, 0);
            #pragma unroll
            for (int r = 0; r < 4; ++r) {
                float v = dacc[r];
                sum[r] += v; sq[r] += v * v; mx[r] = fmaxf(mx[r], v);
            }
        }
    }
    #pragma unroll
    for (int m = 1; m < 16; m <<= 1)
        #pragma unroll
        for (int r = 0; r < 4; ++r) {
            sum[r] += __shfl_xor(sum[r], m);
            sq[r]  += __shfl_xor(sq[r], m);
            mx[r]   = fmaxf(mx[r], __shfl_xor(mx[r], m));
        }
    if (l15 == 0) {
        #pragma unroll
        for (int r = 0; r < 4; ++r) {
            int thw = base + m0 + quad * 4 + r;
            stats[(side * 3 + 0) * THW_ + thw] = sum[r] * (1.f / 576.f);
            stats[(side * 3 + 1) * THW_ + thw] = mx[r];
            stats[(side * 3 + 2) * THW_ + thw] =
                (sq[r] - sum[r] * sum[r] * (1.f / 576.f)) * (1.f / 575.f);
        }
    }
}

// ---------------- k_aux: fused attn (0..287) + agg (288..863) + TR transpose (864..1151)
__global__ __launch_bounds__(256) void k_aux(const float* __restrict__ stats,
                      const float* __restrict__ ca_w1,
                      const float* __restrict__ ca_w2, float* __restrict__ yb,
                      const float* __restrict__ xd,
                      const float* __restrict__ w1, const float* __restrict__ b1,
                      const float* __restrict__ w2, const float* __restrict__ b2,
                      const float* __restrict__ w3, const float* __restrict__ b3,
                      const float* __restrict__ wts, float* __restrict__ agg0,
                      const unsigned short* __restrict__ pch,
                      unsigned short* __restrict__ partb) {
    __shared__ unsigned short ld[64 * 68];
    int blk = blockIdx.x;
    int tid = threadIdx.x;
    if (blk < (2 * THW_) / 256) {
        // ---- attn body ----
        int idx = blk * 256 + tid;
        int side = idx / THW_, thw = idx % THW_;
        int w = thw % W_, h = (thw / W_) % H_, t = thw / HW_;
        const float* avg = stats + (side * 3 + 0) * THW_ + t * HW_;
        const float* mxp = stats + (side * 3 + 1) * THW_ + t * HW_;
        const float* var = stats + (side * 3 + 2) * THW_ + t * HW_;
        float acc = 0.f;
        for (int ki = 0; ki < 3; ++ki) {
            int hh = h - 1 + ki;
            if (hh < 0 || hh >= H_) continue;
            for (int kj = 0; kj < 3; ++kj) {
                int ww = w - 1 + kj;
                if (ww < 0 || ww >= W_) continue;
                int p = hh * W_ + ww;
                int kk = ki * 3 + kj;
                acc += ca_w1[kk] * avg[p] + ca_w1[9 + kk] * mxp[p] + ca_w2[kk] * var[p];
            }
        }
        yb[idx] = sigm(acc);
    } else if (blk < (2 * THW_) / 256 + (RC_ * THW_) / 256) {
        // ---- agg body ----
        int idx = (blk - (2 * THW_) / 256) * 256 + tid;
        int w = idx % W_;
        int h = (idx / W_) % H_;
        int t = (idx / HW_) % T_;
        int r = idx / THW_;
        const float* xr = xd + r * THW_;
        const float* wk_arr[3] = {w1, w2, w3};
        const float* bs_arr[3] = {b1, b2, b3};
        float tot = 0.f;
        for (int m = 0; m < 3; ++m) {
            int dil = m + 1;
            float acc = bs_arr[m][r];
            const float* wk = wk_arr[m] + r * 81;
            for (int kt = 0; kt < 9; ++kt) {
                int tt = t - 4 + kt;
                if (tt < 0 || tt >= T_) continue;
                for (int kh = 0; kh < 3; ++kh) {
                    int hh = h + (kh - 1) * dil;
                    if (hh < 0 || hh >= H_) continue;
                    for (int kw = 0; kw < 3; ++kw) {
                        int wwp = w + (kw - 1) * dil;
                        if (wwp < 0 || wwp >= W_) continue;
                        acc += xr[tt * HW_ + hh * W_ + wwp] * wk[kt * 9 + kh * 3 + kw];
                    }
                }
            }
            tot += acc * wts[m];
        }
        agg0[idx] = tot;
    } else {
        // ---- tr body (was k_tr) ----
        int b2 = blk - ((2 * THW_) / 256 + (RC_ * THW_) / 256);
        int st = b2 / 9;
        int sdt = b2 % 9;
        const unsigned short* src = pch + ((size_t)st * 576 + sdt * 64) * 64;
        for (int i = tid; i < 4096; i += 256) ld[(i >> 6) * 68 + (i & 63)] = src[i];
        __syncthreads();
        unsigned short* dst = partb + (size_t)st * 64 * 576 + sdt * 64;
        for (int i = tid; i < 4096; i += 256) {
            int c = i >> 6, sdl = i & 63;
            dst[(size_t)c * 576 + sdl] = ld[sdl * 68 + c];
        }
    }
}

// ---------------- k_final: R5 structure (side-split, dbuf, wt LDS) + SOFT barriers ------
// Only change vs the 61.9us R5 version: both __syncthreads -> soft_barrier. The global
// prefetch loads (pch/pcl/partb for kt+1) no longer drain at the barriers; they are
// consumed one full iteration later, where the compiler's own vmcnt(N) wait lands.
__global__ __launch_bounds__(256) void k_final(const unsigned short* __restrict__ xbh,
                                               const unsigned short* __restrict__ xbl,
                                               const unsigned short* __restrict__ pch,
                                               const unsigned short* __restrict__ pcl,
                                               const unsigned short* __restrict__ partb,
                                               const float* __restrict__ yb,
                                               const float* __restrict__ weights2,
                                               const float* __restrict__ agg0,
                                               const float* __restrict__ w_back,
                                               float* __restrict__ out) {
    int bid = blockIdx.x;
    int side = bid & 1;
    int tb = bid >> 1;
    int t = tb / 36, hwt = tb % 36;
    int base = t * HW_ + hwt * 64;
    int st = side * 16 + t;
    __shared__ __attribute__((aligned(16))) unsigned short pah[2][64 * SDT_];
    __shared__ __attribute__((aligned(16))) unsigned short pal[2][64 * SDT_];
    __shared__ __attribute__((aligned(16))) unsigned short wt[64 * SDT_];
    int tid = threadIdx.x;
    int lane = tid & 63, wv = tid >> 6;
    int quad = lane >> 4, l15 = lane & 15;
    int m0 = wv * 16;
    const unsigned short* xrh = xbh + (size_t)(base + m0 + l15) * 64;
    const unsigned short* xrl = xbl + (size_t)(base + m0 + l15) * 64;
    short8 ah0 = *(const short8*)&xrh[quad * 8];
    short8 ah1 = *(const short8*)&xrh[32 + quad * 8];
    short8 al0 = *(const short8*)&xrl[quad * 8];
    short8 al1 = *(const short8*)&xrl[32 + quad * 8];
    // gate is uniform over r in the swapped layout: hw row = m0 + l15
    float yvs = yb[(size_t)side * THW_ + base + m0 + l15];
    int sH[4], sC[4];
    #pragma unroll
    for (int k = 0; k < 4; ++k) { int i = tid + k * 256; sH[k] = i >> 4; sC[k] = i & 15; }
    const unsigned short* phb = pch + (size_t)st * 576 * 64;
    const unsigned short* plb = pcl + (size_t)st * 576 * 64;
    const unsigned short* pbb = partb + (size_t)st * 64 * 576 + (size_t)(m0 + l15) * 576;
    uint2 pf_h[4], pf_l[4];
    short8 pbn0, pbn1;
    {   // prefetch kt 0
        #pragma unroll
        for (int k = 0; k < 4; ++k) {
            pf_h[k] = *(const uint2*)&phb[(size_t)sH[k] * 64 + sC[k] * 4];
            pf_l[k] = *(const uint2*)&plb[(size_t)sH[k] * 64 + sC[k] * 4];
        }
        pbn0 = *(const short8*)&pbb[quad * 8];
        pbn1 = *(const short8*)&pbb[32 + quad * 8];
    }
    f32x4 acc[4] = {};
    for (int kt = 0; kt < 9; ++kt) {
        int b = kt & 1;
        // write staged B-tiles from prefetch regs
        #pragma unroll
        for (int k = 0; k < 4; ++k) {
            *(uint2*)&pah[b][sH[k] * SDT_ + sC[k] * 4] = pf_h[k];
            *(uint2*)&pal[b][sH[k] * SDT_ + sC[k] * 4] = pf_l[k];
        }
        short8 pA0 = pbn0, pA1 = pbn1;
        if (kt < 8) {
            const unsigned short* ph = phb + (size_t)(kt + 1) * 64 * 64;
            const unsigned short* pl = plb + (size_t)(kt + 1) * 64 * 64;
            #pragma unroll
            for (int k = 0; k < 4; ++k) {
                pf_h[k] = *(const uint2*)&ph[(size_t)sH[k] * 64 + sC[k] * 4];
                pf_l[k] = *(const uint2*)&pl[(size_t)sH[k] * 64 + sC[k] * 4];
            }
            const unsigned short* pbr = pbb + (kt + 1) * 64;
            pbn0 = *(const short8*)&pbr[quad * 8];
            pbn1 = *(const short8*)&pbr[32 + quad * 8];
        }
        soft_barrier();   // staged tiles visible; prev phase B done reading wt;
                          // prefetch loads stay in flight across the barrier
        // phase A: aff tiles -> sigmoid weights (swapped operands: D[m=sd][n=hw])
        #pragma unroll
        for (int tile = 0; tile < 4; ++tile) {
            short8 bh0 = *(const short8*)&pah[b][(tile * 16 + l15) * SDT_ + quad * 8];
            short8 bh1 = *(const short8*)&pah[b][(tile * 16 + l15) * SDT_ + 32 + quad * 8];
            short8 bl0 = *(const short8*)&pal[b][(tile * 16 + l15) * SDT_ + quad * 8];
            short8 bl1 = *(const short8*)&pal[b][(tile * 16 + l15) * SDT_ + 32 + quad * 8];
            f32x4 dacc = {0.f, 0.f, 0.f, 0.f};
            dacc = __builtin_amdgcn_mfma_f32_16x16x32_bf16(bh0, ah0, dacc, 0, 0, 0);
            dacc = __builtin_amdgcn_mfma_f32_16x16x32_bf16(bh1, ah1, dacc, 0, 0, 0);
            dacc = __builtin_amdgcn_mfma_f32_16x16x32_bf16(bl0, ah0, dacc, 0, 0, 0);
            dacc = __builtin_amdgcn_mfma_f32_16x16x32_bf16(bl1, ah1, dacc, 0, 0, 0);
            dacc = __builtin_amdgcn_mfma_f32_16x16x32_bf16(bh0, al0, dacc, 0, 0, 0);
            dacc = __builtin_amdgcn_mfma_f32_16x16x32_bf16(bh1, al1, dacc, 0, 0, 0);
            // dacc[r] = aff at (sd = kt*64 + tile*16 + quad*4 + r, hw = m0 + l15)
            short4v wq;
            #pragma unroll
            for (int r = 0; r < 4; ++r)
                wq[r] = (short)f2bf(sigm(dacc[r] * yvs) - 0.5f);
            *(short4v*)&wt[(m0 + l15) * SDT_ + tile * 16 + quad * 4] = wq;
        }
        soft_barrier();   // wt visible
        // phase B: P (prefetched A-frag) x wt^T
        #pragma unroll
        for (int tile = 0; tile < 4; ++tile) {
            short8 wb0 = *(const short8*)&wt[(tile * 16 + l15) * SDT_ + quad * 8];
            short8 wb1 = *(const short8*)&wt[(tile * 16 + l15) * SDT_ + 32 + quad * 8];
            acc[tile] = __builtin_amdgcn_mfma_f32_16x16x32_bf16(pA0, wb0, acc[tile], 0, 0, 0);
            acc[tile] = __builtin_amdgcn_mfma_f32_16x16x32_bf16(pA1, wb1, acc[tile], 0, 0, 0);
        }
    }
    float w2s = weights2[side];
    #pragma unroll
    for (int tile = 0; tile < 4; ++tile) {
        int thw = base + tile * 16 + l15;
        #pragma unroll
        for (int r = 0; r < 4; ++r) {
            int c = m0 + quad * 4 + r;
            float a = 0.f;
            #pragma unroll
            for (int rr = 0; rr < RC_; ++rr) a += w_back[c * RC_ + rr] * agg0[rr * THW_ + thw];
            atomicAdd(&out[(size_t)c * THW_ + thw],
                      acc[tile][r] * w2s * (sigm(a) - 0.5f));
        }
    }
}

extern "C" void kernel_launch(void* const* d_in, const int* in_sizes, int n_in,
                              void* d_out, int out_size, void* d_ws, size_t ws_size,
                              hipStream_t stream) {
    const float* x       = (const float*)d_in[0];
    const float* w_dc2   = (const float*)d_in[1];
    const float* w_ofs_l = (const float*)d_in[2];
    const float* b_ofs_l = (const float*)d_in[3];
    const float* w_ofs_r = (const float*)d_in[4];
    const float* b_ofs_r = (const float*)d_in[5];
    const float* ca_w1   = (const float*)d_in[6];
    const float* ca_w2   = (const float*)d_in[7];
    const float* w_down  = (const float*)d_in[8];
    const float* sa1_w   = (const float*)d_in[9];
    const float* sa1_b   = (const float*)d_in[10];
    const float* sa2_w   = (const float*)d_in[11];
    const float* sa2_b   = (const float*)d_in[12];
    const float* sa3_w   = (const float*)d_in[13];
    const float* sa3_b   = (const float*)d_in[14];
    const float* weights = (const float*)d_in[15];
    const float* weights2= (const float*)d_in[16];
    const float* w_back  = (const float*)d_in[17];
    float* out = (float*)d_out;

    // workspace ~24.3 MB (identical layout to previous rounds)
    float* ws    = (float*)d_ws;
    float* x2T   = ws;                               // CTHW_ f32
    float* stats = x2T;                              // overlay: 221,184 f32
    float* yb    = stats + 2 * 3 * THW_;             // 73,728
    float* agg0  = yb + 2 * THW_;                    // 147,456
    unsigned short* partb = (unsigned short*)(agg0 + RC_ * THW_);  // 1,179,648 u16
    float* off   = ws + CTHW_;                       // 36,864 f32
    unsigned short* xbh = (unsigned short*)(off + 2 * T_ * 2 * SD_);  // CTHW_ u16
    unsigned short* xbl = xbh + CTHW_;                                // CTHW_ u16
    unsigned short* pch = xbl + CTHW_;               // 1,179,648 u16
    unsigned short* pcl = pch + 2 * 16 * 576 * 64;   // 1,179,648 u16
    float* xd    = (float*)(pcl + 2 * 16 * 576 * 64); // 147,456 f32

    k_pre<<<THW_ / 64, 256, 0, stream>>>(x, w_dc2, w_down, x2T, xbh, xbl, xd);
    k_off<<<(2 * 16 * 576) / 4, 256, 0, stream>>>(xbh, xbl, x2T, w_ofs_l, b_ofs_l,
                                                  w_ofs_r, b_ofs_r, off);
    k_gs<<<(2 * 16 * 576) / 4, 256, 0, stream>>>(x2T, off, pch, pcl);
    k_stats<<<2 * 16 * 36, 256, 0, stream>>>(xbh, xbl, pch, pcl, stats);
    k_aux<<<(2 * THW_) / 256 + (RC_ * THW_) / 256 + 32 * 9, 256, 0, stream>>>(
        stats, ca_w1, ca_w2, yb, xd, sa1_w, sa1_b, sa2_w, sa2_b,
        sa3_w, sa3_b, weights, agg0, pch, partb);
    k_final<<<2 * 16 * 36, 256, 0, stream>>>(xbh, xbl, pch, pcl, partb, yb, weights2,
                                             agg0, w_back, out);
}

// Round 10
// 217.093 us; speedup vs baseline: 1.6176x; 1.1065x over previous
//
#include <hip/hip_runtime.h>
#include <hip/hip_bf16.h>

#define T_    16
#define C_    64
#define H_    48
#define W_    48
#define HW_   2304
#define THW_  36864
#define CTHW_ 2359296
#define H2_   24
#define W2_   24
#define SD_   576
#define RC_   4
#define SDT_  72    // fp16 LDS tile row stride in halfs (144 B, 16B-multiple)

typedef _Float16 half8 __attribute__((ext_vector_type(8)));
typedef _Float16 half4 __attribute__((ext_vector_type(4)));
typedef float f32x4 __attribute__((ext_vector_type(4)));

__device__ __forceinline__ float sigm(float v) { return 1.f / (1.f + __expf(-v)); }
// Soft barrier: publish LDS ops but leave private-register global loads in flight
// (T4 counted-vmcnt mechanism; compiler inserts its own vmcnt(N) before consumption).
__device__ __forceinline__ void soft_barrier() {
    asm volatile("s_waitcnt lgkmcnt(0)" ::: "memory");
    __builtin_amdgcn_s_barrier();
}

// ---------------- k_pre: x2T GEMM + fp16 x transpose + xd = w_down@x -------------------
// fp16 single-precision path (11-bit mantissa) replaces the bf16 hi/lo split: one
// buffer instead of two, one MFMA term instead of three downstream.
__global__ __launch_bounds__(256) void k_pre(const float* __restrict__ x,
                                             const float* __restrict__ w,
                                             const float* __restrict__ w_down,
                                             float* __restrict__ x2T,
                                             _Float16* __restrict__ xfh,
                                             float* __restrict__ xd) {
    int base = blockIdx.x * 64;
    __shared__ float wl[64 * 65];
    __shared__ float xt[4096];
    __shared__ float ld[64 * 65];
    __shared__ float wd[256];
    int tid = threadIdx.x;
    for (int i = tid; i < 4096; i += 256) wl[(i >> 6) * 65 + (i & 63)] = w[i];
    for (int i = tid; i < 4096; i += 256) {
        float v = x[(size_t)(i >> 6) * THW_ + base + (i & 63)];
        xt[i] = v;
        ld[(i >> 6) * 65 + (i & 63)] = v;
    }
    if (tid < 256) wd[tid] = w_down[tid];
    __syncthreads();
    {
        int o_grp = tid >> 4, u_grp = tid & 15;
        float acc[4][4] = {};
        const float4* xt4 = (const float4*)xt;
        for (int c = 0; c < 64; ++c) {
            float xa[4];
            *(float4*)xa = xt4[c * 16 + u_grp];
            #pragma unroll
            for (int i = 0; i < 4; ++i) {
                float wv = wl[(o_grp * 4 + i) * 65 + c];
                #pragma unroll
                for (int g = 0; g < 4; ++g) acc[i][g] += wv * xa[g];
            }
        }
        #pragma unroll
        for (int g = 0; g < 4; ++g) {
            float4 v = make_float4(acc[0][g], acc[1][g], acc[2][g], acc[3][g]);
            *(float4*)&x2T[(size_t)(base + u_grp * 4 + g) * 64 + o_grp * 4] = v;
        }
    }
    {
        int r = tid >> 6, u = tid & 63;
        float a = 0.f;
        #pragma unroll 8
        for (int c = 0; c < 64; ++c) a += wd[r * 64 + c] * xt[c * 64 + u];
        xd[(size_t)r * THW_ + base + u] = a;
    }
    for (int i = tid; i < 4096; i += 256) {
        int u = i >> 6, c = i & 63;
        xfh[(size_t)(base + u) * 64 + c] = (_Float16)ld[c * 65 + u];
    }
}

// ---------------- k_off: coalesced x-read via xfh ([thw][c] fp16) ----------------------
__global__ __launch_bounds__(256) void k_off(const _Float16* __restrict__ xfh,
                                             const float* __restrict__ x2T,
                                             const float* __restrict__ w_l,
                                             const float* __restrict__ b_l,
                                             const float* __restrict__ w_r,
                                             const float* __restrict__ b_r,
                                             float* __restrict__ off) {
    __shared__ float wlds[2304];
    int tid = threadIdx.x;
    for (int i = tid; i < 2304; i += 256) wlds[i] = (i < 1152) ? w_l[i] : w_r[i - 1152];
    __syncthreads();
    int wg = blockIdx.x * 4 + (tid >> 6);
    int lane = tid & 63;
    int j = wg % 24, i = (wg / 24) % 24, t = (wg / 576) % 16, side = wg / 9216;
    int ts = (side == 0) ? min(t + 1, T_ - 1) : max(t - 1, 0);
    const float* wp = wlds + side * 1152;
    const _Float16* xhb = xfh + ((size_t)t * HW_) * 64 + lane;
    const float* x2l = x2T + (size_t)ts * HW_ * 64 + lane;
    float a0 = 0.f, a1 = 0.f;
    for (int ki = 0; ki < 3; ++ki) {
        int hh = 2 * i - 1 + ki;
        if (hh < 0 || hh >= H_) continue;
        for (int kj = 0; kj < 3; ++kj) {
            int ww = 2 * j - 1 + kj;
            if (ww < 0 || ww >= W_) continue;
            int pos = hh * W_ + ww;
            float s = (float)xhb[(size_t)pos * 64] + x2l[(size_t)pos * 64];
            int tap = ki * 3 + kj;
            a0 += s * wp[lane * 9 + tap];
            a1 += s * wp[576 + lane * 9 + tap];
        }
    }
    #pragma unroll
    for (int m = 32; m >= 1; m >>= 1) {
        a0 += __shfl_xor(a0, m);
        a1 += __shfl_xor(a1, m);
    }
    if (lane == 0) {
        const float* bb = (side == 0) ? b_l : b_r;
        int ob = (side * 16 + t) * 1152 + i * 24 + j;
        off[ob] = a0 + bb[0];
        off[ob + 576] = a1 + bb[1];
    }
}

// ---------------- k_gs: grid-sample -> fp16 pxh (single buffer) ------------------------
__global__ __launch_bounds__(256) void k_gs(const float* __restrict__ x2T,
                                            const float* __restrict__ off,
                                            _Float16* __restrict__ pxh) {
    int wg = blockIdx.x * 4 + (threadIdx.x >> 6);
    int lane = threadIdx.x & 63;
    int sd = wg % 576;
    int t = (wg / 576) % 16;
    int side = wg / 9216;
    int d = sd % W2_, s = sd / W2_;
    const float* offp = off + (side * 16 + t) * 1152;
    float v0 = 2.f * (float)d + offp[sd];
    float v1 = 2.f * (float)s + offp[576 + sd];
    float xf = 48.f * v0 / 23.f - 0.5f;
    float yf = 48.f * v1 / 23.f - 0.5f;
    float x0 = floorf(xf), y0 = floorf(yf);
    int ix0 = (int)x0, iy0 = (int)y0;
    float fx = xf - x0, fy = yf - y0;
    float w00 = (1.f - fx) * (1.f - fy), w10 = fx * (1.f - fy);
    float w01 = (1.f - fx) * fy,         w11 = fx * fy;
    bool vx0 = (ix0 >= 0 && ix0 < W_), vx1 = (ix0 + 1 >= 0 && ix0 + 1 < W_);
    bool vy0 = (iy0 >= 0 && iy0 < H_), vy1 = (iy0 + 1 >= 0 && iy0 + 1 < H_);
    int cx0 = min(max(ix0, 0), W_ - 1), cx1 = min(max(ix0 + 1, 0), W_ - 1);
    int cy0 = min(max(iy0, 0), H_ - 1), cy1 = min(max(iy0 + 1, 0), H_ - 1);
    float m00 = (vx0 && vy0) ? w00 : 0.f;
    float m10 = (vx1 && vy0) ? w10 : 0.f;
    float m01 = (vx0 && vy1) ? w01 : 0.f;
    float m11 = (vx1 && vy1) ? w11 : 0.f;
    int ts = (side == 0) ? min(t + 1, T_ - 1) : max(t - 1, 0);
    const float* img = x2T + (size_t)ts * HW_ * 64;
    float val = m00 * img[(size_t)(cy0 * W_ + cx0) * 64 + lane]
              + m10 * img[(size_t)(cy0 * W_ + cx1) * 64 + lane]
              + m01 * img[(size_t)(cy1 * W_ + cx0) * 64 + lane]
              + m11 * img[(size_t)(cy1 * W_ + cx1) * 64 + lane];
    size_t idx = ((size_t)(side * 16 + t) * 576 + sd) * 64 + lane;
    pxh[idx] = (_Float16)val;
}

// ---------------- k_stats: side-split, dbuf stage (fp16, single buffer), soft barrier --
__global__ __launch_bounds__(256) void k_stats(const _Float16* __restrict__ xfh,
                                               const _Float16* __restrict__ pxh,
                                               float* __restrict__ stats) {
    int bid = blockIdx.x;
    int side = bid & 1;
    int tb = bid >> 1;
    int t = tb / 36, hwt = tb % 36;
    int base = t * HW_ + hwt * 64;
    __shared__ __attribute__((aligned(16))) _Float16 ps[2][64 * SDT_];
    int tid = threadIdx.x;
    int lane = tid & 63, wv = tid >> 6;
    int quad = lane >> 4, l15 = lane & 15;
    int m0 = wv * 16;
    const _Float16* xr = xfh + (size_t)(base + m0 + l15) * 64;
    half8 a0 = *(const half8*)&xr[quad * 8];
    half8 a1 = *(const half8*)&xr[32 + quad * 8];
    int sH[4], sC[4];
    #pragma unroll
    for (int k = 0; k < 4; ++k) { int i = tid + k * 256; sH[k] = i >> 4; sC[k] = i & 15; }
    const _Float16* phb = pxh + (size_t)(side * 16 + t) * 576 * 64;
    uint2 pf[4];
    #pragma unroll
    for (int k = 0; k < 4; ++k)
        pf[k] = *(const uint2*)&phb[(size_t)sH[k] * 64 + sC[k] * 4];
    float sum[4] = {}, sq[4] = {};
    float mx[4] = {-1e30f, -1e30f, -1e30f, -1e30f};
    for (int kt = 0; kt < 9; ++kt) {
        int b = kt & 1;
        #pragma unroll
        for (int k = 0; k < 4; ++k)
            *(uint2*)&ps[b][sH[k] * SDT_ + sC[k] * 4] = pf[k];
        if (kt < 8) {
            const _Float16* ph = phb + (size_t)(kt + 1) * 4096;
            #pragma unroll
            for (int k = 0; k < 4; ++k)
                pf[k] = *(const uint2*)&ph[(size_t)sH[k] * 64 + sC[k] * 4];
        }
        soft_barrier();   // stage(kt) visible; prefetch loads stay in flight
        #pragma unroll
        for (int tile = 0; tile < 4; ++tile) {
            half8 b0 = *(const half8*)&ps[b][(tile * 16 + l15) * SDT_ + quad * 8];
            half8 b1 = *(const half8*)&ps[b][(tile * 16 + l15) * SDT_ + 32 + quad * 8];
            f32x4 dacc = {0.f, 0.f, 0.f, 0.f};
            dacc = __builtin_amdgcn_mfma_f32_16x16x32_f16(a0, b0, dacc, 0, 0, 0);
            dacc = __builtin_amdgcn_mfma_f32_16x16x32_f16(a1, b1, dacc, 0, 0, 0);
            #pragma unroll
            for (int r = 0; r < 4; ++r) {
                float v = dacc[r];
                sum[r] += v; sq[r] += v * v; mx[r] = fmaxf(mx[r], v);
            }
        }
    }
    #pragma unroll
    for (int m = 1; m < 16; m <<= 1)
        #pragma unroll
        for (int r = 0; r < 4; ++r) {
            sum[r] += __shfl_xor(sum[r], m);
            sq[r]  += __shfl_xor(sq[r], m);
            mx[r]   = fmaxf(mx[r], __shfl_xor(mx[r], m));
        }
    if (l15 == 0) {
        #pragma unroll
        for (int r = 0; r < 4; ++r) {
            int thw = base + m0 + quad * 4 + r;
            stats[(side * 3 + 0) * THW_ + thw] = sum[r] * (1.f / 576.f);
            stats[(side * 3 + 1) * THW_ + thw] = mx[r];
            stats[(side * 3 + 2) * THW_ + thw] =
                (sq[r] - sum[r] * sum[r] * (1.f / 576.f)) * (1.f / 575.f);
        }
    }
}

// ---------------- k_aux: fused attn (0..287) + agg (288..863) + TR transpose (864..1151)
__global__ __launch_bounds__(256) void k_aux(const float* __restrict__ stats,
                      const float* __restrict__ ca_w1,
                      const float* __restrict__ ca_w2, float* __restrict__ yb,
                      const float* __restrict__ xd,
                      const float* __restrict__ w1, const float* __restrict__ b1,
                      const float* __restrict__ w2, const float* __restrict__ b2,
                      const float* __restrict__ w3, const float* __restrict__ b3,
                      const float* __restrict__ wts, float* __restrict__ agg0,
                      const _Float16* __restrict__ pxh,
                      _Float16* __restrict__ partb) {
    __shared__ unsigned short ld[64 * 68];
    int blk = blockIdx.x;
    int tid = threadIdx.x;
    if (blk < (2 * THW_) / 256) {
        // ---- attn body ----
        int idx = blk * 256 + tid;
        int side = idx / THW_, thw = idx % THW_;
        int w = thw % W_, h = (thw / W_) % H_, t = thw / HW_;
        const float* avg = stats + (side * 3 + 0) * THW_ + t * HW_;
        const float* mxp = stats + (side * 3 + 1) * THW_ + t * HW_;
        const float* var = stats + (side * 3 + 2) * THW_ + t * HW_;
        float acc = 0.f;
        for (int ki = 0; ki < 3; ++ki) {
            int hh = h - 1 + ki;
            if (hh < 0 || hh >= H_) continue;
            for (int kj = 0; kj < 3; ++kj) {
                int ww = w - 1 + kj;
                if (ww < 0 || ww >= W_) continue;
                int p = hh * W_ + ww;
                int kk = ki * 3 + kj;
                acc += ca_w1[kk] * avg[p] + ca_w1[9 + kk] * mxp[p] + ca_w2[kk] * var[p];
            }
        }
        yb[idx] = sigm(acc);
    } else if (blk < (2 * THW_) / 256 + (RC_ * THW_) / 256) {
        // ---- agg body ----
        int idx = (blk - (2 * THW_) / 256) * 256 + tid;
        int w = idx % W_;
        int h = (idx / W_) % H_;
        int t = (idx / HW_) % T_;
        int r = idx / THW_;
        const float* xr = xd + r * THW_;
        const float* wk_arr[3] = {w1, w2, w3};
        const float* bs_arr[3] = {b1, b2, b3};
        float tot = 0.f;
        for (int m = 0; m < 3; ++m) {
            int dil = m + 1;
            float acc = bs_arr[m][r];
            const float* wk = wk_arr[m] + r * 81;
            for (int kt = 0; kt < 9; ++kt) {
                int tt = t - 4 + kt;
                if (tt < 0 || tt >= T_) continue;
                for (int kh = 0; kh < 3; ++kh) {
                    int hh = h + (kh - 1) * dil;
                    if (hh < 0 || hh >= H_) continue;
                    for (int kw = 0; kw < 3; ++kw) {
                        int wwp = w + (kw - 1) * dil;
                        if (wwp < 0 || wwp >= W_) continue;
                        acc += xr[tt * HW_ + hh * W_ + wwp] * wk[kt * 9 + kh * 3 + kw];
                    }
                }
            }
            tot += acc * wts[m];
        }
        agg0[idx] = tot;
    } else {
        // ---- tr body: transpose pxh[st][sd][c] -> partb[st][c][sd] (fp16 bit copy) ----
        int b2 = blk - ((2 * THW_) / 256 + (RC_ * THW_) / 256);
        int st = b2 / 9;
        int sdt = b2 % 9;
        const unsigned short* src = (const unsigned short*)pxh + ((size_t)st * 576 + sdt * 64) * 64;
        for (int i = tid; i < 4096; i += 256) ld[(i >> 6) * 68 + (i & 63)] = src[i];
        __syncthreads();
        unsigned short* dst = (unsigned short*)partb + (size_t)st * 64 * 576 + sdt * 64;
        for (int i = tid; i < 4096; i += 256) {
            int c = i >> 6, sdl = i & 63;
            dst[(size_t)c * 576 + sdl] = ld[sdl * 68 + c];
        }
    }
}

// ---------------- k_final: fp16 single-path; side-split, dbuf, wt LDS, soft barriers ---
// Per wave-iter vs bf16-split R5: MFMA 32->16, LDS ops 36->24, staging loads 8->4.
__global__ __launch_bounds__(256) void k_final(const _Float16* __restrict__ xfh,
                                               const _Float16* __restrict__ pxh,
                                               const _Float16* __restrict__ partb,
                                               const float* __restrict__ yb,
                                               const float* __restrict__ weights2,
                                               const float* __restrict__ agg0,
                                               const float* __restrict__ w_back,
                                               float* __restrict__ out) {
    int bid = blockIdx.x;
    int side = bid & 1;
    int tb = bid >> 1;
    int t = tb / 36, hwt = tb % 36;
    int base = t * HW_ + hwt * 64;
    int st = side * 16 + t;
    __shared__ __attribute__((aligned(16))) _Float16 ps[2][64 * SDT_];
    __shared__ __attribute__((aligned(16))) _Float16 wt[64 * SDT_];
    int tid = threadIdx.x;
    int lane = tid & 63, wv = tid >> 6;
    int quad = lane >> 4, l15 = lane & 15;
    int m0 = wv * 16;
    const _Float16* xr = xfh + (size_t)(base + m0 + l15) * 64;
    half8 a0 = *(const half8*)&xr[quad * 8];
    half8 a1 = *(const half8*)&xr[32 + quad * 8];
    // gate is uniform over r in the swapped layout: hw row = m0 + l15
    float yvs = yb[(size_t)side * THW_ + base + m0 + l15];
    int sH[4], sC[4];
    #pragma unroll
    for (int k = 0; k < 4; ++k) { int i = tid + k * 256; sH[k] = i >> 4; sC[k] = i & 15; }
    const _Float16* phb = pxh + (size_t)st * 576 * 64;
    const _Float16* pbb = partb + (size_t)st * 64 * 576 + (size_t)(m0 + l15) * 576;
    uint2 pf[4];
    half8 pbn0, pbn1;
    {   // prefetch kt 0
        #pragma unroll
        for (int k = 0; k < 4; ++k)
            pf[k] = *(const uint2*)&phb[(size_t)sH[k] * 64 + sC[k] * 4];
        pbn0 = *(const half8*)&pbb[quad * 8];
        pbn1 = *(const half8*)&pbb[32 + quad * 8];
    }
    f32x4 acc[4] = {};
    for (int kt = 0; kt < 9; ++kt) {
        int b = kt & 1;
        // write staged B-tile from prefetch regs
        #pragma unroll
        for (int k = 0; k < 4; ++k)
            *(uint2*)&ps[b][sH[k] * SDT_ + sC[k] * 4] = pf[k];
        half8 pA0 = pbn0, pA1 = pbn1;
        if (kt < 8) {
            const _Float16* ph = phb + (size_t)(kt + 1) * 4096;
            #pragma unroll
            for (int k = 0; k < 4; ++k)
                pf[k] = *(const uint2*)&ph[(size_t)sH[k] * 64 + sC[k] * 4];
            const _Float16* pbr = pbb + (kt + 1) * 64;
            pbn0 = *(const half8*)&pbr[quad * 8];
            pbn1 = *(const half8*)&pbr[32 + quad * 8];
        }
        soft_barrier();   // stage[b] visible; prev phase B done reading wt;
                          // prefetch loads stay in flight across the barrier
        // phase A: aff tiles -> sigmoid weights (swapped operands: D[m=sd][n=hw])
        #pragma unroll
        for (int tile = 0; tile < 4; ++tile) {
            half8 b0 = *(const half8*)&ps[b][(tile * 16 + l15) * SDT_ + quad * 8];
            half8 b1 = *(const half8*)&ps[b][(tile * 16 + l15) * SDT_ + 32 + quad * 8];
            f32x4 dacc = {0.f, 0.f, 0.f, 0.f};
            dacc = __builtin_amdgcn_mfma_f32_16x16x32_f16(b0, a0, dacc, 0, 0, 0);
            dacc = __builtin_amdgcn_mfma_f32_16x16x32_f16(b1, a1, dacc, 0, 0, 0);
            // dacc[r] = aff at (sd = kt*64 + tile*16 + quad*4 + r, hw = m0 + l15)
            half4 wq;
            #pragma unroll
            for (int r = 0; r < 4; ++r)
                wq[r] = (_Float16)(sigm(dacc[r] * yvs) - 0.5f);
            *(half4*)&wt[(m0 + l15) * SDT_ + tile * 16 + quad * 4] = wq;
        }
        soft_barrier();   // wt visible
        // phase B: P (prefetched A-frag) x wt^T
        #pragma unroll
        for (int tile = 0; tile < 4; ++tile) {
            half8 wb0 = *(const half8*)&wt[(tile * 16 + l15) * SDT_ + quad * 8];
            half8 wb1 = *(const half8*)&wt[(tile * 16 + l15) * SDT_ + 32 + quad * 8];
            acc[tile] = __builtin_amdgcn_mfma_f32_16x16x32_f16(pA0, wb0, acc[tile], 0, 0, 0);
            acc[tile] = __builtin_amdgcn_mfma_f32_16x16x32_f16(pA1, wb1, acc[tile], 0, 0, 0);
        }
    }
    float w2s = weights2[side];
    #pragma unroll
    for (int tile = 0; tile < 4; ++tile) {
        int thw = base + tile * 16 + l15;
        #pragma unroll
        for (int r = 0; r < 4; ++r) {
            int c = m0 + quad * 4 + r;
            float a = 0.f;
            #pragma unroll
            for (int rr = 0; rr < RC_; ++rr) a += w_back[c * RC_ + rr] * agg0[rr * THW_ + thw];
            atomicAdd(&out[(size_t)c * THW_ + thw],
                      acc[tile][r] * w2s * (sigm(a) - 0.5f));
        }
    }
}

extern "C" void kernel_launch(void* const* d_in, const int* in_sizes, int n_in,
                              void* d_out, int out_size, void* d_ws, size_t ws_size,
                              hipStream_t stream) {
    const float* x       = (const float*)d_in[0];
    const float* w_dc2   = (const float*)d_in[1];
    const float* w_ofs_l = (const float*)d_in[2];
    const float* b_ofs_l = (const float*)d_in[3];
    const float* w_ofs_r = (const float*)d_in[4];
    const float* b_ofs_r = (const float*)d_in[5];
    const float* ca_w1   = (const float*)d_in[6];
    const float* ca_w2   = (const float*)d_in[7];
    const float* w_down  = (const float*)d_in[8];
    const float* sa1_w   = (const float*)d_in[9];
    const float* sa1_b   = (const float*)d_in[10];
    const float* sa2_w   = (const float*)d_in[11];
    const float* sa2_b   = (const float*)d_in[12];
    const float* sa3_w   = (const float*)d_in[13];
    const float* sa3_b   = (const float*)d_in[14];
    const float* weights = (const float*)d_in[15];
    const float* weights2= (const float*)d_in[16];
    const float* w_back  = (const float*)d_in[17];
    float* out = (float*)d_out;

    // workspace (same slot offsets as previous rounds; pcl/xbl slots now unused)
    float* ws    = (float*)d_ws;
    float* x2T   = ws;                               // CTHW_ f32
    float* stats = x2T;                              // overlay: 221,184 f32
    float* yb    = stats + 2 * 3 * THW_;             // 73,728
    float* agg0  = yb + 2 * THW_;                    // 147,456
    _Float16* partb = (_Float16*)(agg0 + RC_ * THW_);  // 1,179,648 fp16
    float* off   = ws + CTHW_;                       // 36,864 f32
    _Float16* xfh = (_Float16*)(off + 2 * T_ * 2 * SD_);  // CTHW_ fp16 (old xbh slot)
    _Float16* pxh = (_Float16*)((unsigned short*)xfh + 2 * CTHW_);  // old pch slot
    float* xd    = (float*)((unsigned short*)pxh + 2 * (2 * 16 * 576 * 64)); // old slot arith kept safe

    k_pre<<<THW_ / 64, 256, 0, stream>>>(x, w_dc2, w_down, x2T, xfh, xd);
    k_off<<<(2 * 16 * 576) / 4, 256, 0, stream>>>(xfh, x2T, w_ofs_l, b_ofs_l,
                                                  w_ofs_r, b_ofs_r, off);
    k_gs<<<(2 * 16 * 576) / 4, 256, 0, stream>>>(x2T, off, pxh);
    k_stats<<<2 * 16 * 36, 256, 0, stream>>>(xfh, pxh, stats);
    k_aux<<<(2 * THW_) / 256 + (RC_ * THW_) / 256 + 32 * 9, 256, 0, stream>>>(
        stats, ca_w1, ca_w2, yb, xd, sa1_w, sa1_b, sa2_w, sa2_b,
        sa3_w, sa3_b, weights, agg0, pxh, partb);
    k_final<<<2 * 16 * 36, 256, 0, stream>>>(xfh, pxh, partb, yb, weights2,
                                             agg0, w_back, out);
}

// Round 11
// 206.314 us; speedup vs baseline: 1.7021x; 1.0522x over previous
//
#include <hip/hip_runtime.h>
#include <hip/hip_bf16.h>

#define T_    16
#define C_    64
#define H_    48
#define W_    48
#define HW_   2304
#define THW_  36864
#define CTHW_ 2359296
#define H2_   24
#define W2_   24
#define SD_   576
#define RC_   4
#define SDT_  72    // fp16 LDS tile row stride in halfs (144 B, 16B-multiple)

typedef _Float16 half8 __attribute__((ext_vector_type(8)));
typedef _Float16 half4 __attribute__((ext_vector_type(4)));
typedef float f32x4 __attribute__((ext_vector_type(4)));

// Fast sigmoid: v_rcp_f32 (1 inst, ~1ulp) instead of IEEE f32 divide, which hipcc
// lowers to div_scale+div_fmas+div_fixup (~8 insts) without fast-math.
__device__ __forceinline__ float sigm(float v) {
    return __builtin_amdgcn_rcpf(1.f + __expf(-v));
}
// Soft barrier: publish LDS ops but leave private-register global loads in flight
// (T4 counted-vmcnt mechanism; compiler inserts its own vmcnt(N) before consumption).
__device__ __forceinline__ void soft_barrier() {
    asm volatile("s_waitcnt lgkmcnt(0)" ::: "memory");
    __builtin_amdgcn_s_barrier();
}

// ---------------- k_pre: x2T GEMM + fp16 x transpose + xd = w_down@x -------------------
__global__ __launch_bounds__(256) void k_pre(const float* __restrict__ x,
                                             const float* __restrict__ w,
                                             const float* __restrict__ w_down,
                                             float* __restrict__ x2T,
                                             _Float16* __restrict__ xfh,
                                             float* __restrict__ xd) {
    int base = blockIdx.x * 64;
    __shared__ float wl[64 * 65];
    __shared__ float xt[4096];
    __shared__ float ld[64 * 65];
    __shared__ float wd[256];
    int tid = threadIdx.x;
    for (int i = tid; i < 4096; i += 256) wl[(i >> 6) * 65 + (i & 63)] = w[i];
    for (int i = tid; i < 4096; i += 256) {
        float v = x[(size_t)(i >> 6) * THW_ + base + (i & 63)];
        xt[i] = v;
        ld[(i >> 6) * 65 + (i & 63)] = v;
    }
    if (tid < 256) wd[tid] = w_down[tid];
    __syncthreads();
    {
        int o_grp = tid >> 4, u_grp = tid & 15;
        float acc[4][4] = {};
        const float4* xt4 = (const float4*)xt;
        for (int c = 0; c < 64; ++c) {
            float xa[4];
            *(float4*)xa = xt4[c * 16 + u_grp];
            #pragma unroll
            for (int i = 0; i < 4; ++i) {
                float wv = wl[(o_grp * 4 + i) * 65 + c];
                #pragma unroll
                for (int g = 0; g < 4; ++g) acc[i][g] += wv * xa[g];
            }
        }
        #pragma unroll
        for (int g = 0; g < 4; ++g) {
            float4 v = make_float4(acc[0][g], acc[1][g], acc[2][g], acc[3][g]);
            *(float4*)&x2T[(size_t)(base + u_grp * 4 + g) * 64 + o_grp * 4] = v;
        }
    }
    {
        int r = tid >> 6, u = tid & 63;
        float a = 0.f;
        #pragma unroll 8
        for (int c = 0; c < 64; ++c) a += wd[r * 64 + c] * xt[c * 64 + u];
        xd[(size_t)r * THW_ + base + u] = a;
    }
    for (int i = tid; i < 4096; i += 256) {
        int u = i >> 6, c = i & 63;
        xfh[(size_t)(base + u) * 64 + c] = (_Float16)ld[c * 65 + u];
    }
}

// ---------------- k_off: coalesced x-read via xfh ([thw][c] fp16) ----------------------
__global__ __launch_bounds__(256) void k_off(const _Float16* __restrict__ xfh,
                                             const float* __restrict__ x2T,
                                             const float* __restrict__ w_l,
                                             const float* __restrict__ b_l,
                                             const float* __restrict__ w_r,
                                             const float* __restrict__ b_r,
                                             float* __restrict__ off) {
    __shared__ float wlds[2304];
    int tid = threadIdx.x;
    for (int i = tid; i < 2304; i += 256) wlds[i] = (i < 1152) ? w_l[i] : w_r[i - 1152];
    __syncthreads();
    int wg = blockIdx.x * 4 + (tid >> 6);
    int lane = tid & 63;
    int j = wg % 24, i = (wg / 24) % 24, t = (wg / 576) % 16, side = wg / 9216;
    int ts = (side == 0) ? min(t + 1, T_ - 1) : max(t - 1, 0);
    const float* wp = wlds + side * 1152;
    const _Float16* xhb = xfh + ((size_t)t * HW_) * 64 + lane;
    const float* x2l = x2T + (size_t)ts * HW_ * 64 + lane;
    float a0 = 0.f, a1 = 0.f;
    for (int ki = 0; ki < 3; ++ki) {
        int hh = 2 * i - 1 + ki;
        if (hh < 0 || hh >= H_) continue;
        for (int kj = 0; kj < 3; ++kj) {
            int ww = 2 * j - 1 + kj;
            if (ww < 0 || ww >= W_) continue;
            int pos = hh * W_ + ww;
            float s = (float)xhb[(size_t)pos * 64] + x2l[(size_t)pos * 64];
            int tap = ki * 3 + kj;
            a0 += s * wp[lane * 9 + tap];
            a1 += s * wp[576 + lane * 9 + tap];
        }
    }
    #pragma unroll
    for (int m = 32; m >= 1; m >>= 1) {
        a0 += __shfl_xor(a0, m);
        a1 += __shfl_xor(a1, m);
    }
    if (lane == 0) {
        const float* bb = (side == 0) ? b_l : b_r;
        int ob = (side * 16 + t) * 1152 + i * 24 + j;
        off[ob] = a0 + bb[0];
        off[ob + 576] = a1 + bb[1];
    }
}

// ---------------- k_gs: grid-sample -> fp16 pxh (single buffer) ------------------------
__global__ __launch_bounds__(256) void k_gs(const float* __restrict__ x2T,
                                            const float* __restrict__ off,
                                            _Float16* __restrict__ pxh) {
    int wg = blockIdx.x * 4 + (threadIdx.x >> 6);
    int lane = threadIdx.x & 63;
    int sd = wg % 576;
    int t = (wg / 576) % 16;
    int side = wg / 9216;
    int d = sd % W2_, s = sd / W2_;
    const float* offp = off + (side * 16 + t) * 1152;
    float v0 = 2.f * (float)d + offp[sd];
    float v1 = 2.f * (float)s + offp[576 + sd];
    float xf = 48.f * v0 / 23.f - 0.5f;
    float yf = 48.f * v1 / 23.f - 0.5f;
    float x0 = floorf(xf), y0 = floorf(yf);
    int ix0 = (int)x0, iy0 = (int)y0;
    float fx = xf - x0, fy = yf - y0;
    float w00 = (1.f - fx) * (1.f - fy), w10 = fx * (1.f - fy);
    float w01 = (1.f - fx) * fy,         w11 = fx * fy;
    bool vx0 = (ix0 >= 0 && ix0 < W_), vx1 = (ix0 + 1 >= 0 && ix0 + 1 < W_);
    bool vy0 = (iy0 >= 0 && iy0 < H_), vy1 = (iy0 + 1 >= 0 && iy0 + 1 < H_);
    int cx0 = min(max(ix0, 0), W_ - 1), cx1 = min(max(ix0 + 1, 0), W_ - 1);
    int cy0 = min(max(iy0, 0), H_ - 1), cy1 = min(max(iy0 + 1, 0), H_ - 1);
    float m00 = (vx0 && vy0) ? w00 : 0.f;
    float m10 = (vx1 && vy0) ? w10 : 0.f;
    float m01 = (vx0 && vy1) ? w01 : 0.f;
    float m11 = (vx1 && vy1) ? w11 : 0.f;
    int ts = (side == 0) ? min(t + 1, T_ - 1) : max(t - 1, 0);
    const float* img = x2T + (size_t)ts * HW_ * 64;
    float val = m00 * img[(size_t)(cy0 * W_ + cx0) * 64 + lane]
              + m10 * img[(size_t)(cy0 * W_ + cx1) * 64 + lane]
              + m01 * img[(size_t)(cy1 * W_ + cx0) * 64 + lane]
              + m11 * img[(size_t)(cy1 * W_ + cx1) * 64 + lane];
    size_t idx = ((size_t)(side * 16 + t) * 576 + sd) * 64 + lane;
    pxh[idx] = (_Float16)val;
}

// ---------------- k_stats: side-split, dbuf stage (fp16, single buffer), soft barrier --
__global__ __launch_bounds__(256) void k_stats(const _Float16* __restrict__ xfh,
                                               const _Float16* __restrict__ pxh,
                                               float* __restrict__ stats) {
    int bid = blockIdx.x;
    int side = bid & 1;
    int tb = bid >> 1;
    int t = tb / 36, hwt = tb % 36;
    int base = t * HW_ + hwt * 64;
    __shared__ __attribute__((aligned(16))) _Float16 ps[2][64 * SDT_];
    int tid = threadIdx.x;
    int lane = tid & 63, wv = tid >> 6;
    int quad = lane >> 4, l15 = lane & 15;
    int m0 = wv * 16;
    const _Float16* xr = xfh + (size_t)(base + m0 + l15) * 64;
    half8 a0 = *(const half8*)&xr[quad * 8];
    half8 a1 = *(const half8*)&xr[32 + quad * 8];
    int sH[4], sC[4];
    #pragma unroll
    for (int k = 0; k < 4; ++k) { int i = tid + k * 256; sH[k] = i >> 4; sC[k] = i & 15; }
    const _Float16* phb = pxh + (size_t)(side * 16 + t) * 576 * 64;
    uint2 pf[4];
    #pragma unroll
    for (int k = 0; k < 4; ++k)
        pf[k] = *(const uint2*)&phb[(size_t)sH[k] * 64 + sC[k] * 4];
    float sum[4] = {}, sq[4] = {};
    float mx[4] = {-1e30f, -1e30f, -1e30f, -1e30f};
    for (int kt = 0; kt < 9; ++kt) {
        int b = kt & 1;
        #pragma unroll
        for (int k = 0; k < 4; ++k)
            *(uint2*)&ps[b][sH[k] * SDT_ + sC[k] * 4] = pf[k];
        if (kt < 8) {
            const _Float16* ph = phb + (size_t)(kt + 1) * 4096;
            #pragma unroll
            for (int k = 0; k < 4; ++k)
                pf[k] = *(const uint2*)&ph[(size_t)sH[k] * 64 + sC[k] * 4];
        }
        soft_barrier();   // stage(kt) visible; prefetch loads stay in flight
        #pragma unroll
        for (int tile = 0; tile < 4; ++tile) {
            half8 b0 = *(const half8*)&ps[b][(tile * 16 + l15) * SDT_ + quad * 8];
            half8 b1 = *(const half8*)&ps[b][(tile * 16 + l15) * SDT_ + 32 + quad * 8];
            f32x4 dacc = {0.f, 0.f, 0.f, 0.f};
            dacc = __builtin_amdgcn_mfma_f32_16x16x32_f16(a0, b0, dacc, 0, 0, 0);
            dacc = __builtin_amdgcn_mfma_f32_16x16x32_f16(a1, b1, dacc, 0, 0, 0);
            #pragma unroll
            for (int r = 0; r < 4; ++r) {
                float v = dacc[r];
                sum[r] += v; sq[r] += v * v; mx[r] = fmaxf(mx[r], v);
            }
        }
    }
    #pragma unroll
    for (int m = 1; m < 16; m <<= 1)
        #pragma unroll
        for (int r = 0; r < 4; ++r) {
            sum[r] += __shfl_xor(sum[r], m);
            sq[r]  += __shfl_xor(sq[r], m);
            mx[r]   = fmaxf(mx[r], __shfl_xor(mx[r], m));
        }
    if (l15 == 0) {
        #pragma unroll
        for (int r = 0; r < 4; ++r) {
            int thw = base + m0 + quad * 4 + r;
            stats[(side * 3 + 0) * THW_ + thw] = sum[r] * (1.f / 576.f);
            stats[(side * 3 + 1) * THW_ + thw] = mx[r];
            stats[(side * 3 + 2) * THW_ + thw] =
                (sq[r] - sum[r] * sum[r] * (1.f / 576.f)) * (1.f / 575.f);
        }
    }
}

// ---------------- k_aux: fused attn (0..287) + agg (288..863) + TR transpose (864..1151)
__global__ __launch_bounds__(256) void k_aux(const float* __restrict__ stats,
                      const float* __restrict__ ca_w1,
                      const float* __restrict__ ca_w2, float* __restrict__ yb,
                      const float* __restrict__ xd,
                      const float* __restrict__ w1, const float* __restrict__ b1,
                      const float* __restrict__ w2, const float* __restrict__ b2,
                      const float* __restrict__ w3, const float* __restrict__ b3,
                      const float* __restrict__ wts, float* __restrict__ agg0,
                      const _Float16* __restrict__ pxh,
                      _Float16* __restrict__ partb) {
    __shared__ unsigned short ld[64 * 68];
    int blk = blockIdx.x;
    int tid = threadIdx.x;
    if (blk < (2 * THW_) / 256) {
        // ---- attn body ----
        int idx = blk * 256 + tid;
        int side = idx / THW_, thw = idx % THW_;
        int w = thw % W_, h = (thw / W_) % H_, t = thw / HW_;
        const float* avg = stats + (side * 3 + 0) * THW_ + t * HW_;
        const float* mxp = stats + (side * 3 + 1) * THW_ + t * HW_;
        const float* var = stats + (side * 3 + 2) * THW_ + t * HW_;
        float acc = 0.f;
        for (int ki = 0; ki < 3; ++ki) {
            int hh = h - 1 + ki;
            if (hh < 0 || hh >= H_) continue;
            for (int kj = 0; kj < 3; ++kj) {
                int ww = w - 1 + kj;
                if (ww < 0 || ww >= W_) continue;
                int p = hh * W_ + ww;
                int kk = ki * 3 + kj;
                acc += ca_w1[kk] * avg[p] + ca_w1[9 + kk] * mxp[p] + ca_w2[kk] * var[p];
            }
        }
        yb[idx] = sigm(acc);
    } else if (blk < (2 * THW_) / 256 + (RC_ * THW_) / 256) {
        // ---- agg body ----
        int idx = (blk - (2 * THW_) / 256) * 256 + tid;
        int w = idx % W_;
        int h = (idx / W_) % H_;
        int t = (idx / HW_) % T_;
        int r = idx / THW_;
        const float* xr = xd + r * THW_;
        const float* wk_arr[3] = {w1, w2, w3};
        const float* bs_arr[3] = {b1, b2, b3};
        float tot = 0.f;
        for (int m = 0; m < 3; ++m) {
            int dil = m + 1;
            float acc = bs_arr[m][r];
            const float* wk = wk_arr[m] + r * 81;
            for (int kt = 0; kt < 9; ++kt) {
                int tt = t - 4 + kt;
                if (tt < 0 || tt >= T_) continue;
                for (int kh = 0; kh < 3; ++kh) {
                    int hh = h + (kh - 1) * dil;
                    if (hh < 0 || hh >= H_) continue;
                    for (int kw = 0; kw < 3; ++kw) {
                        int wwp = w + (kw - 1) * dil;
                        if (wwp < 0 || wwp >= W_) continue;
                        acc += xr[tt * HW_ + hh * W_ + wwp] * wk[kt * 9 + kh * 3 + kw];
                    }
                }
            }
            tot += acc * wts[m];
        }
        agg0[idx] = tot;
    } else {
        // ---- tr body: transpose pxh[st][sd][c] -> partb[st][c][sd] (fp16 bit copy) ----
        int b2 = blk - ((2 * THW_) / 256 + (RC_ * THW_) / 256);
        int st = b2 / 9;
        int sdt = b2 % 9;
        const unsigned short* src = (const unsigned short*)pxh + ((size_t)st * 576 + sdt * 64) * 64;
        for (int i = tid; i < 4096; i += 256) ld[(i >> 6) * 68 + (i & 63)] = src[i];
        __syncthreads();
        unsigned short* dst = (unsigned short*)partb + (size_t)st * 64 * 576 + sdt * 64;
        for (int i = tid; i < 4096; i += 256) {
            int c = i >> 6, sdl = i & 63;
            dst[(size_t)c * 576 + sdl] = ld[sdl * 68 + c];
        }
    }
}

// ---------------- k_final: fp16; fast sigmoid chain (exp2-srcmod + rcp), prescaled gate -
// Phase A sigmoid: yvs*log2e folded into the loop-invariant x-fragments (8 pk_mul once);
// per element the chain is v_exp_f32(-dacc) [asm srcmod] + v_add + v_rcp + v_sub + cvt
// = 5 insts, vs ~14 before (IEEE divide was div_scale/div_fmas/div_fixup).
__global__ __launch_bounds__(256) void k_final(const _Float16* __restrict__ xfh,
                                               const _Float16* __restrict__ pxh,
                                               const _Float16* __restrict__ partb,
                                               const float* __restrict__ yb,
                                               const float* __restrict__ weights2,
                                               const float* __restrict__ agg0,
                                               const float* __restrict__ w_back,
                                               float* __restrict__ out) {
    int bid = blockIdx.x;
    int side = bid & 1;
    int tb = bid >> 1;
    int t = tb / 36, hwt = tb % 36;
    int base = t * HW_ + hwt * 64;
    int st = side * 16 + t;
    __shared__ __attribute__((aligned(16))) _Float16 ps[2][64 * SDT_];
    __shared__ __attribute__((aligned(16))) _Float16 wt[64 * SDT_];
    int tid = threadIdx.x;
    int lane = tid & 63, wv = tid >> 6;
    int quad = lane >> 4, l15 = lane & 15;
    int m0 = wv * 16;
    const _Float16* xr = xfh + (size_t)(base + m0 + l15) * 64;
    half8 a0 = *(const half8*)&xr[quad * 8];
    half8 a1 = *(const half8*)&xr[32 + quad * 8];
    // gate uniform over r: hw row = m0 + l15. Fold yvs*log2e into the x-frags so
    // phase-A MFMA output is already z*log2e for sigm(z) = 1/(1+2^(-z*log2e)).
    float yvs = yb[(size_t)side * THW_ + base + m0 + l15];
    _Float16 ysh = (_Float16)(yvs * 1.44269504f);
    half8 a0s = a0 * ysh;
    half8 a1s = a1 * ysh;
    int sH[4], sC[4];
    #pragma unroll
    for (int k = 0; k < 4; ++k) { int i = tid + k * 256; sH[k] = i >> 4; sC[k] = i & 15; }
    const _Float16* phb = pxh + (size_t)st * 576 * 64;
    const _Float16* pbb = partb + (size_t)st * 64 * 576 + (size_t)(m0 + l15) * 576;
    uint2 pf[4];
    half8 pbn0, pbn1;
    {   // prefetch kt 0
        #pragma unroll
        for (int k = 0; k < 4; ++k)
            pf[k] = *(const uint2*)&phb[(size_t)sH[k] * 64 + sC[k] * 4];
        pbn0 = *(const half8*)&pbb[quad * 8];
        pbn1 = *(const half8*)&pbb[32 + quad * 8];
    }
    f32x4 acc[4] = {};
    for (int kt = 0; kt < 9; ++kt) {
        int b = kt & 1;
        // write staged B-tile from prefetch regs
        #pragma unroll
        for (int k = 0; k < 4; ++k)
            *(uint2*)&ps[b][sH[k] * SDT_ + sC[k] * 4] = pf[k];
        half8 pA0 = pbn0, pA1 = pbn1;
        if (kt < 8) {
            const _Float16* ph = phb + (size_t)(kt + 1) * 4096;
            #pragma unroll
            for (int k = 0; k < 4; ++k)
                pf[k] = *(const uint2*)&ph[(size_t)sH[k] * 64 + sC[k] * 4];
            const _Float16* pbr = pbb + (kt + 1) * 64;
            pbn0 = *(const half8*)&pbr[quad * 8];
            pbn1 = *(const half8*)&pbr[32 + quad * 8];
        }
        soft_barrier();   // stage[b] visible; prev phase B done reading wt;
                          // prefetch loads stay in flight across the barrier
        // phase A: aff tiles -> sigmoid weights (swapped operands: D[m=sd][n=hw])
        #pragma unroll
        for (int tile = 0; tile < 4; ++tile) {
            half8 b0 = *(const half8*)&ps[b][(tile * 16 + l15) * SDT_ + quad * 8];
            half8 b1 = *(const half8*)&ps[b][(tile * 16 + l15) * SDT_ + 32 + quad * 8];
            f32x4 dacc = {0.f, 0.f, 0.f, 0.f};
            dacc = __builtin_amdgcn_mfma_f32_16x16x32_f16(b0, a0s, dacc, 0, 0, 0);
            dacc = __builtin_amdgcn_mfma_f32_16x16x32_f16(b1, a1s, dacc, 0, 0, 0);
            // dacc[r] = aff*yvs*log2e at (sd = kt*64+tile*16+quad*4+r, hw = m0+l15)
            half4 wq;
            #pragma unroll
            for (int r = 0; r < 4; ++r) {
                float e;
                asm("v_exp_f32 %0, -%1" : "=v"(e) : "v"(dacc[r]));   // 2^(-dacc)
                float w = __builtin_amdgcn_rcpf(1.f + e) - 0.5f;
                wq[r] = (_Float16)w;
            }
            *(half4*)&wt[(m0 + l15) * SDT_ + tile * 16 + quad * 4] = wq;
        }
        soft_barrier();   // wt visible
        // phase B: P (prefetched A-frag) x wt^T
        #pragma unroll
        for (int tile = 0; tile < 4; ++tile) {
            half8 wb0 = *(const half8*)&wt[(tile * 16 + l15) * SDT_ + quad * 8];
            half8 wb1 = *(const half8*)&wt[(tile * 16 + l15) * SDT_ + 32 + quad * 8];
            acc[tile] = __builtin_amdgcn_mfma_f32_16x16x32_f16(pA0, wb0, acc[tile], 0, 0, 0);
            acc[tile] = __builtin_amdgcn_mfma_f32_16x16x32_f16(pA1, wb1, acc[tile], 0, 0, 0);
        }
    }
    float w2s = weights2[side];
    #pragma unroll
    for (int tile = 0; tile < 4; ++tile) {
        int thw = base + tile * 16 + l15;
        #pragma unroll
        for (int r = 0; r < 4; ++r) {
            int c = m0 + quad * 4 + r;
            float a = 0.f;
            #pragma unroll
            for (int rr = 0; rr < RC_; ++rr) a += w_back[c * RC_ + rr] * agg0[rr * THW_ + thw];
            atomicAdd(&out[(size_t)c * THW_ + thw],
                      acc[tile][r] * w2s * (sigm(a) - 0.5f));
        }
    }
}

extern "C" void kernel_launch(void* const* d_in, const int* in_sizes, int n_in,
                              void* d_out, int out_size, void* d_ws, size_t ws_size,
                              hipStream_t stream) {
    const float* x       = (const float*)d_in[0];
    const float* w_dc2   = (const float*)d_in[1];
    const float* w_ofs_l = (const float*)d_in[2];
    const float* b_ofs_l = (const float*)d_in[3];
    const float* w_ofs_r = (const float*)d_in[4];
    const float* b_ofs_r = (const float*)d_in[5];
    const float* ca_w1   = (const float*)d_in[6];
    const float* ca_w2   = (const float*)d_in[7];
    const float* w_down  = (const float*)d_in[8];
    const float* sa1_w   = (const float*)d_in[9];
    const float* sa1_b   = (const float*)d_in[10];
    const float* sa2_w   = (const float*)d_in[11];
    const float* sa2_b   = (const float*)d_in[12];
    const float* sa3_w   = (const float*)d_in[13];
    const float* sa3_b   = (const float*)d_in[14];
    const float* weights = (const float*)d_in[15];
    const float* weights2= (const float*)d_in[16];
    const float* w_back  = (const float*)d_in[17];
    float* out = (float*)d_out;

    // workspace (same slot offsets as previous rounds; pcl/xbl slots now unused)
    float* ws    = (float*)d_ws;
    float* x2T   = ws;                               // CTHW_ f32
    float* stats = x2T;                              // overlay: 221,184 f32
    float* yb    = stats + 2 * 3 * THW_;             // 73,728
    float* agg0  = yb + 2 * THW_;                    // 147,456
    _Float16* partb = (_Float16*)(agg0 + RC_ * THW_);  // 1,179,648 fp16
    float* off   = ws + CTHW_;                       // 36,864 f32
    _Float16* xfh = (_Float16*)(off + 2 * T_ * 2 * SD_);  // CTHW_ fp16 (old xbh slot)
    _Float16* pxh = (_Float16*)((unsigned short*)xfh + 2 * CTHW_);  // old pch slot
    float* xd    = (float*)((unsigned short*)pxh + 2 * (2 * 16 * 576 * 64)); // old slot arith kept safe

    k_pre<<<THW_ / 64, 256, 0, stream>>>(x, w_dc2, w_down, x2T, xfh, xd);
    k_off<<<(2 * 16 * 576) / 4, 256, 0, stream>>>(xfh, x2T, w_ofs_l, b_ofs_l,
                                                  w_ofs_r, b_ofs_r, off);
    k_gs<<<(2 * 16 * 576) / 4, 256, 0, stream>>>(x2T, off, pxh);
    k_stats<<<2 * 16 * 36, 256, 0, stream>>>(xfh, pxh, stats);
    k_aux<<<(2 * THW_) / 256 + (RC_ * THW_) / 256 + 32 * 9, 256, 0, stream>>>(
        stats, ca_w1, ca_w2, yb, xd, sa1_w, sa1_b, sa2_w, sa2_b,
        sa3_w, sa3_b, weights, agg0, pxh, partb);
    k_final<<<2 * 16 * 36, 256, 0, stream>>>(xfh, pxh, partb, yb, weights2,
                                             agg0, w_back, out);
}

// Round 12
// 203.703 us; speedup vs baseline: 1.7239x; 1.0128x over previous
//
#include <hip/hip_runtime.h>
#include <hip/hip_bf16.h>

#define T_    16
#define C_    64
#define H_    48
#define W_    48
#define HW_   2304
#define THW_  36864
#define CTHW_ 2359296
#define H2_   24
#define W2_   24
#define SD_   576
#define RC_   4
#define SDT_  72    // fp16 LDS tile row stride in halfs (144 B, 16B-multiple)

typedef _Float16 half8 __attribute__((ext_vector_type(8)));
typedef _Float16 half4 __attribute__((ext_vector_type(4)));
typedef float f32x4 __attribute__((ext_vector_type(4)));

// Fast sigmoid: v_rcp_f32 (1 inst, ~1ulp) instead of IEEE f32 divide, which hipcc
// lowers to div_scale+div_fmas+div_fixup (~8 insts) without fast-math.
__device__ __forceinline__ float sigm(float v) {
    return __builtin_amdgcn_rcpf(1.f + __expf(-v));
}
// Soft barrier: publish LDS ops but leave private-register global loads in flight
// (T4 counted-vmcnt mechanism; compiler inserts its own vmcnt(N) before consumption).
__device__ __forceinline__ void soft_barrier() {
    asm volatile("s_waitcnt lgkmcnt(0)" ::: "memory");
    __builtin_amdgcn_s_barrier();
}

// ---------------- k_pre: x2T GEMM + fp16 x transpose + xd = w_down@x -------------------
__global__ __launch_bounds__(256) void k_pre(const float* __restrict__ x,
                                             const float* __restrict__ w,
                                             const float* __restrict__ w_down,
                                             float* __restrict__ x2T,
                                             _Float16* __restrict__ xfh,
                                             float* __restrict__ xd) {
    int base = blockIdx.x * 64;
    __shared__ float wl[64 * 65];
    __shared__ float xt[4096];
    __shared__ float ld[64 * 65];
    __shared__ float wd[256];
    int tid = threadIdx.x;
    for (int i = tid; i < 4096; i += 256) wl[(i >> 6) * 65 + (i & 63)] = w[i];
    for (int i = tid; i < 4096; i += 256) {
        float v = x[(size_t)(i >> 6) * THW_ + base + (i & 63)];
        xt[i] = v;
        ld[(i >> 6) * 65 + (i & 63)] = v;
    }
    if (tid < 256) wd[tid] = w_down[tid];
    __syncthreads();
    {
        int o_grp = tid >> 4, u_grp = tid & 15;
        float acc[4][4] = {};
        const float4* xt4 = (const float4*)xt;
        for (int c = 0; c < 64; ++c) {
            float xa[4];
            *(float4*)xa = xt4[c * 16 + u_grp];
            #pragma unroll
            for (int i = 0; i < 4; ++i) {
                float wv = wl[(o_grp * 4 + i) * 65 + c];
                #pragma unroll
                for (int g = 0; g < 4; ++g) acc[i][g] += wv * xa[g];
            }
        }
        #pragma unroll
        for (int g = 0; g < 4; ++g) {
            float4 v = make_float4(acc[0][g], acc[1][g], acc[2][g], acc[3][g]);
            *(float4*)&x2T[(size_t)(base + u_grp * 4 + g) * 64 + o_grp * 4] = v;
        }
    }
    {
        int r = tid >> 6, u = tid & 63;
        float a = 0.f;
        #pragma unroll 8
        for (int c = 0; c < 64; ++c) a += wd[r * 64 + c] * xt[c * 64 + u];
        xd[(size_t)r * THW_ + base + u] = a;
    }
    for (int i = tid; i < 4096; i += 256) {
        int u = i >> 6, c = i & 63;
        xfh[(size_t)(base + u) * 64 + c] = (_Float16)ld[c * 65 + u];
    }
}

// ---------------- k_gs: FUSED offset-conv + grid-sample ------------------------------
// k_off wave (side,t,i,j) fed exactly one k_gs wave (side,t,sd=i*24+j) — 1:1 mapping.
// Fused: compute a0,a1 via the 9-tap conv + xor-reduce (all 64 lanes end with the
// sums), then grid-sample directly with v = 2*{d,s} + a + bias in registers.
// Kills one launch + the off round-trip + the duplicate x2T tap read pass.
__global__ __launch_bounds__(256) void k_gs(const _Float16* __restrict__ xfh,
                                            const float* __restrict__ x2T,
                                            const float* __restrict__ w_l,
                                            const float* __restrict__ b_l,
                                            const float* __restrict__ w_r,
                                            const float* __restrict__ b_r,
                                            _Float16* __restrict__ pxh) {
    __shared__ float wlds[2304];
    int tid = threadIdx.x;
    for (int i = tid; i < 2304; i += 256) wlds[i] = (i < 1152) ? w_l[i] : w_r[i - 1152];
    __syncthreads();
    int wg = blockIdx.x * 4 + (tid >> 6);
    int lane = tid & 63;
    int sd = wg % 576;
    int t = (wg / 576) % 16;
    int side = wg / 9216;
    int j = sd % W2_, i = sd / W2_;          // j=d (x), i=s (y)
    int ts = (side == 0) ? min(t + 1, T_ - 1) : max(t - 1, 0);
    // ---- offset conv (was k_off) ----
    const float* wp = wlds + side * 1152;
    const _Float16* xhb = xfh + ((size_t)t * HW_) * 64 + lane;
    const float* x2l = x2T + (size_t)ts * HW_ * 64 + lane;
    float a0 = 0.f, a1 = 0.f;
    for (int ki = 0; ki < 3; ++ki) {
        int hh = 2 * i - 1 + ki;
        if (hh < 0 || hh >= H_) continue;
        for (int kj = 0; kj < 3; ++kj) {
            int ww = 2 * j - 1 + kj;
            if (ww < 0 || ww >= W_) continue;
            int pos = hh * W_ + ww;
            float s = (float)xhb[(size_t)pos * 64] + x2l[(size_t)pos * 64];
            int tap = ki * 3 + kj;
            a0 += s * wp[lane * 9 + tap];
            a1 += s * wp[576 + lane * 9 + tap];
        }
    }
    #pragma unroll
    for (int m = 32; m >= 1; m >>= 1) {
        a0 += __shfl_xor(a0, m);
        a1 += __shfl_xor(a1, m);
    }
    const float* bb = (side == 0) ? b_l : b_r;
    // ---- grid-sample (was k_gs body); offp[sd]=a0+bb[0], offp[576+sd]=a1+bb[1] ----
    float v0 = 2.f * (float)j + (a0 + bb[0]);
    float v1 = 2.f * (float)i + (a1 + bb[1]);
    float xf = 48.f * v0 / 23.f - 0.5f;
    float yf = 48.f * v1 / 23.f - 0.5f;
    float x0 = floorf(xf), y0 = floorf(yf);
    int ix0 = (int)x0, iy0 = (int)y0;
    float fx = xf - x0, fy = yf - y0;
    float w00 = (1.f - fx) * (1.f - fy), w10 = fx * (1.f - fy);
    float w01 = (1.f - fx) * fy,         w11 = fx * fy;
    bool vx0 = (ix0 >= 0 && ix0 < W_), vx1 = (ix0 + 1 >= 0 && ix0 + 1 < W_);
    bool vy0 = (iy0 >= 0 && iy0 < H_), vy1 = (iy0 + 1 >= 0 && iy0 + 1 < H_);
    int cx0 = min(max(ix0, 0), W_ - 1), cx1 = min(max(ix0 + 1, 0), W_ - 1);
    int cy0 = min(max(iy0, 0), H_ - 1), cy1 = min(max(iy0 + 1, 0), H_ - 1);
    float m00 = (vx0 && vy0) ? w00 : 0.f;
    float m10 = (vx1 && vy0) ? w10 : 0.f;
    float m01 = (vx0 && vy1) ? w01 : 0.f;
    float m11 = (vx1 && vy1) ? w11 : 0.f;
    const float* img = x2T + (size_t)ts * HW_ * 64;
    float val = m00 * img[(size_t)(cy0 * W_ + cx0) * 64 + lane]
              + m10 * img[(size_t)(cy0 * W_ + cx1) * 64 + lane]
              + m01 * img[(size_t)(cy1 * W_ + cx0) * 64 + lane]
              + m11 * img[(size_t)(cy1 * W_ + cx1) * 64 + lane];
    size_t idx = ((size_t)(side * 16 + t) * 576 + sd) * 64 + lane;
    pxh[idx] = (_Float16)val;
}

// ---------------- k_stats: side-split, dbuf stage (fp16, single buffer), soft barrier --
__global__ __launch_bounds__(256) void k_stats(const _Float16* __restrict__ xfh,
                                               const _Float16* __restrict__ pxh,
                                               float* __restrict__ stats) {
    int bid = blockIdx.x;
    int side = bid & 1;
    int tb = bid >> 1;
    int t = tb / 36, hwt = tb % 36;
    int base = t * HW_ + hwt * 64;
    __shared__ __attribute__((aligned(16))) _Float16 ps[2][64 * SDT_];
    int tid = threadIdx.x;
    int lane = tid & 63, wv = tid >> 6;
    int quad = lane >> 4, l15 = lane & 15;
    int m0 = wv * 16;
    const _Float16* xr = xfh + (size_t)(base + m0 + l15) * 64;
    half8 a0 = *(const half8*)&xr[quad * 8];
    half8 a1 = *(const half8*)&xr[32 + quad * 8];
    int sH[4], sC[4];
    #pragma unroll
    for (int k = 0; k < 4; ++k) { int i = tid + k * 256; sH[k] = i >> 4; sC[k] = i & 15; }
    const _Float16* phb = pxh + (size_t)(side * 16 + t) * 576 * 64;
    uint2 pf[4];
    #pragma unroll
    for (int k = 0; k < 4; ++k)
        pf[k] = *(const uint2*)&phb[(size_t)sH[k] * 64 + sC[k] * 4];
    float sum[4] = {}, sq[4] = {};
    float mx[4] = {-1e30f, -1e30f, -1e30f, -1e30f};
    for (int kt = 0; kt < 9; ++kt) {
        int b = kt & 1;
        #pragma unroll
        for (int k = 0; k < 4; ++k)
            *(uint2*)&ps[b][sH[k] * SDT_ + sC[k] * 4] = pf[k];
        if (kt < 8) {
            const _Float16* ph = phb + (size_t)(kt + 1) * 4096;
            #pragma unroll
            for (int k = 0; k < 4; ++k)
                pf[k] = *(const uint2*)&ph[(size_t)sH[k] * 64 + sC[k] * 4];
        }
        soft_barrier();   // stage(kt) visible; prefetch loads stay in flight
        #pragma unroll
        for (int tile = 0; tile < 4; ++tile) {
            half8 b0 = *(const half8*)&ps[b][(tile * 16 + l15) * SDT_ + quad * 8];
            half8 b1 = *(const half8*)&ps[b][(tile * 16 + l15) * SDT_ + 32 + quad * 8];
            f32x4 dacc = {0.f, 0.f, 0.f, 0.f};
            dacc = __builtin_amdgcn_mfma_f32_16x16x32_f16(a0, b0, dacc, 0, 0, 0);
            dacc = __builtin_amdgcn_mfma_f32_16x16x32_f16(a1, b1, dacc, 0, 0, 0);
            #pragma unroll
            for (int r = 0; r < 4; ++r) {
                float v = dacc[r];
                sum[r] += v; sq[r] += v * v; mx[r] = fmaxf(mx[r], v);
            }
        }
    }
    #pragma unroll
    for (int m = 1; m < 16; m <<= 1)
        #pragma unroll
        for (int r = 0; r < 4; ++r) {
            sum[r] += __shfl_xor(sum[r], m);
            sq[r]  += __shfl_xor(sq[r], m);
            mx[r]   = fmaxf(mx[r], __shfl_xor(mx[r], m));
        }
    if (l15 == 0) {
        #pragma unroll
        for (int r = 0; r < 4; ++r) {
            int thw = base + m0 + quad * 4 + r;
            stats[(side * 3 + 0) * THW_ + thw] = sum[r] * (1.f / 576.f);
            stats[(side * 3 + 1) * THW_ + thw] = mx[r];
            stats[(side * 3 + 2) * THW_ + thw] =
                (sq[r] - sum[r] * sum[r] * (1.f / 576.f)) * (1.f / 575.f);
        }
    }
}

// ---------------- k_aux: fused attn (0..287) + agg (288..863) + TR transpose (864..1151)
__global__ __launch_bounds__(256) void k_aux(const float* __restrict__ stats,
                      const float* __restrict__ ca_w1,
                      const float* __restrict__ ca_w2, float* __restrict__ yb,
                      const float* __restrict__ xd,
                      const float* __restrict__ w1, const float* __restrict__ b1,
                      const float* __restrict__ w2, const float* __restrict__ b2,
                      const float* __restrict__ w3, const float* __restrict__ b3,
                      const float* __restrict__ wts, float* __restrict__ agg0,
                      const _Float16* __restrict__ pxh,
                      _Float16* __restrict__ partb) {
    __shared__ unsigned short ld[64 * 68];
    int blk = blockIdx.x;
    int tid = threadIdx.x;
    if (blk < (2 * THW_) / 256) {
        // ---- attn body ----
        int idx = blk * 256 + tid;
        int side = idx / THW_, thw = idx % THW_;
        int w = thw % W_, h = (thw / W_) % H_, t = thw / HW_;
        const float* avg = stats + (side * 3 + 0) * THW_ + t * HW_;
        const float* mxp = stats + (side * 3 + 1) * THW_ + t * HW_;
        const float* var = stats + (side * 3 + 2) * THW_ + t * HW_;
        float acc = 0.f;
        for (int ki = 0; ki < 3; ++ki) {
            int hh = h - 1 + ki;
            if (hh < 0 || hh >= H_) continue;
            for (int kj = 0; kj < 3; ++kj) {
                int ww = w - 1 + kj;
                if (ww < 0 || ww >= W_) continue;
                int p = hh * W_ + ww;
                int kk = ki * 3 + kj;
                acc += ca_w1[kk] * avg[p] + ca_w1[9 + kk] * mxp[p] + ca_w2[kk] * var[p];
            }
        }
        yb[idx] = sigm(acc);
    } else if (blk < (2 * THW_) / 256 + (RC_ * THW_) / 256) {
        // ---- agg body ----
        int idx = (blk - (2 * THW_) / 256) * 256 + tid;
        int w = idx % W_;
        int h = (idx / W_) % H_;
        int t = (idx / HW_) % T_;
        int r = idx / THW_;
        const float* xr = xd + r * THW_;
        const float* wk_arr[3] = {w1, w2, w3};
        const float* bs_arr[3] = {b1, b2, b3};
        float tot = 0.f;
        for (int m = 0; m < 3; ++m) {
            int dil = m + 1;
            float acc = bs_arr[m][r];
            const float* wk = wk_arr[m] + r * 81;
            for (int kt = 0; kt < 9; ++kt) {
                int tt = t - 4 + kt;
                if (tt < 0 || tt >= T_) continue;
                for (int kh = 0; kh < 3; ++kh) {
                    int hh = h + (kh - 1) * dil;
                    if (hh < 0 || hh >= H_) continue;
                    for (int kw = 0; kw < 3; ++kw) {
                        int wwp = w + (kw - 1) * dil;
                        if (wwp < 0 || wwp >= W_) continue;
                        acc += xr[tt * HW_ + hh * W_ + wwp] * wk[kt * 9 + kh * 3 + kw];
                    }
                }
            }
            tot += acc * wts[m];
        }
        agg0[idx] = tot;
    } else {
        // ---- tr body: transpose pxh[st][sd][c] -> partb[st][c][sd] (fp16 bit copy) ----
        int b2 = blk - ((2 * THW_) / 256 + (RC_ * THW_) / 256);
        int st = b2 / 9;
        int sdt = b2 % 9;
        const unsigned short* src = (const unsigned short*)pxh + ((size_t)st * 576 + sdt * 64) * 64;
        for (int i = tid; i < 4096; i += 256) ld[(i >> 6) * 68 + (i & 63)] = src[i];
        __syncthreads();
        unsigned short* dst = (unsigned short*)partb + (size_t)st * 64 * 576 + sdt * 64;
        for (int i = tid; i < 4096; i += 256) {
            int c = i >> 6, sdl = i & 63;
            dst[(size_t)c * 576 + sdl] = ld[sdl * 68 + c];
        }
    }
}

// ---------------- k_final: fp16; fast sigmoid chain (exp2-srcmod + rcp), prescaled gate -
__global__ __launch_bounds__(256) void k_final(const _Float16* __restrict__ xfh,
                                               const _Float16* __restrict__ pxh,
                                               const _Float16* __restrict__ partb,
                                               const float* __restrict__ yb,
                                               const float* __restrict__ weights2,
                                               const float* __restrict__ agg0,
                                               const float* __restrict__ w_back,
                                               float* __restrict__ out) {
    int bid = blockIdx.x;
    int side = bid & 1;
    int tb = bid >> 1;
    int t = tb / 36, hwt = tb % 36;
    int base = t * HW_ + hwt * 64;
    int st = side * 16 + t;
    __shared__ __attribute__((aligned(16))) _Float16 ps[2][64 * SDT_];
    __shared__ __attribute__((aligned(16))) _Float16 wt[64 * SDT_];
    int tid = threadIdx.x;
    int lane = tid & 63, wv = tid >> 6;
    int quad = lane >> 4, l15 = lane & 15;
    int m0 = wv * 16;
    const _Float16* xr = xfh + (size_t)(base + m0 + l15) * 64;
    half8 a0 = *(const half8*)&xr[quad * 8];
    half8 a1 = *(const half8*)&xr[32 + quad * 8];
    // gate uniform over r: hw row = m0 + l15. Fold yvs*log2e into the x-frags so
    // phase-A MFMA output is already z*log2e for sigm(z) = 1/(1+2^(-z*log2e)).
    float yvs = yb[(size_t)side * THW_ + base + m0 + l15];
    _Float16 ysh = (_Float16)(yvs * 1.44269504f);
    half8 a0s = a0 * ysh;
    half8 a1s = a1 * ysh;
    int sH[4], sC[4];
    #pragma unroll
    for (int k = 0; k < 4; ++k) { int i = tid + k * 256; sH[k] = i >> 4; sC[k] = i & 15; }
    const _Float16* phb = pxh + (size_t)st * 576 * 64;
    const _Float16* pbb = partb + (size_t)st * 64 * 576 + (size_t)(m0 + l15) * 576;
    uint2 pf[4];
    half8 pbn0, pbn1;
    {   // prefetch kt 0
        #pragma unroll
        for (int k = 0; k < 4; ++k)
            pf[k] = *(const uint2*)&phb[(size_t)sH[k] * 64 + sC[k] * 4];
        pbn0 = *(const half8*)&pbb[quad * 8];
        pbn1 = *(const half8*)&pbb[32 + quad * 8];
    }
    f32x4 acc[4] = {};
    for (int kt = 0; kt < 9; ++kt) {
        int b = kt & 1;
        // write staged B-tile from prefetch regs
        #pragma unroll
        for (int k = 0; k < 4; ++k)
            *(uint2*)&ps[b][sH[k] * SDT_ + sC[k] * 4] = pf[k];
        half8 pA0 = pbn0, pA1 = pbn1;
        if (kt < 8) {
            const _Float16* ph = phb + (size_t)(kt + 1) * 4096;
            #pragma unroll
            for (int k = 0; k < 4; ++k)
                pf[k] = *(const uint2*)&ph[(size_t)sH[k] * 64 + sC[k] * 4];
            const _Float16* pbr = pbb + (kt + 1) * 64;
            pbn0 = *(const half8*)&pbr[quad * 8];
            pbn1 = *(const half8*)&pbr[32 + quad * 8];
        }
        soft_barrier();   // stage[b] visible; prev phase B done reading wt;
                          // prefetch loads stay in flight across the barrier
        // phase A: aff tiles -> sigmoid weights (swapped operands: D[m=sd][n=hw])
        #pragma unroll
        for (int tile = 0; tile < 4; ++tile) {
            half8 b0 = *(const half8*)&ps[b][(tile * 16 + l15) * SDT_ + quad * 8];
            half8 b1 = *(const half8*)&ps[b][(tile * 16 + l15) * SDT_ + 32 + quad * 8];
            f32x4 dacc = {0.f, 0.f, 0.f, 0.f};
            dacc = __builtin_amdgcn_mfma_f32_16x16x32_f16(b0, a0s, dacc, 0, 0, 0);
            dacc = __builtin_amdgcn_mfma_f32_16x16x32_f16(b1, a1s, dacc, 0, 0, 0);
            // dacc[r] = aff*yvs*log2e at (sd = kt*64+tile*16+quad*4+r, hw = m0+l15)
            half4 wq;
            #pragma unroll
            for (int r = 0; r < 4; ++r) {
                float e;
                asm("v_exp_f32 %0, -%1" : "=v"(e) : "v"(dacc[r]));   // 2^(-dacc)
                float w = __builtin_amdgcn_rcpf(1.f + e) - 0.5f;
                wq[r] = (_Float16)w;
            }
            *(half4*)&wt[(m0 + l15) * SDT_ + tile * 16 + quad * 4] = wq;
        }
        soft_barrier();   // wt visible
        // phase B: P (prefetched A-frag) x wt^T
        #pragma unroll
        for (int tile = 0; tile < 4; ++tile) {
            half8 wb0 = *(const half8*)&wt[(tile * 16 + l15) * SDT_ + quad * 8];
            half8 wb1 = *(const half8*)&wt[(tile * 16 + l15) * SDT_ + 32 + quad * 8];
            acc[tile] = __builtin_amdgcn_mfma_f32_16x16x32_f16(pA0, wb0, acc[tile], 0, 0, 0);
            acc[tile] = __builtin_amdgcn_mfma_f32_16x16x32_f16(pA1, wb1, acc[tile], 0, 0, 0);
        }
    }
    float w2s = weights2[side];
    #pragma unroll
    for (int tile = 0; tile < 4; ++tile) {
        int thw = base + tile * 16 + l15;
        #pragma unroll
        for (int r = 0; r < 4; ++r) {
            int c = m0 + quad * 4 + r;
            float a = 0.f;
            #pragma unroll
            for (int rr = 0; rr < RC_; ++rr) a += w_back[c * RC_ + rr] * agg0[rr * THW_ + thw];
            atomicAdd(&out[(size_t)c * THW_ + thw],
                      acc[tile][r] * w2s * (sigm(a) - 0.5f));
        }
    }
}

extern "C" void kernel_launch(void* const* d_in, const int* in_sizes, int n_in,
                              void* d_out, int out_size, void* d_ws, size_t ws_size,
                              hipStream_t stream) {
    const float* x       = (const float*)d_in[0];
    const float* w_dc2   = (const float*)d_in[1];
    const float* w_ofs_l = (const float*)d_in[2];
    const float* b_ofs_l = (const float*)d_in[3];
    const float* w_ofs_r = (const float*)d_in[4];
    const float* b_ofs_r = (const float*)d_in[5];
    const float* ca_w1   = (const float*)d_in[6];
    const float* ca_w2   = (const float*)d_in[7];
    const float* w_down  = (const float*)d_in[8];
    const float* sa1_w   = (const float*)d_in[9];
    const float* sa1_b   = (const float*)d_in[10];
    const float* sa2_w   = (const float*)d_in[11];
    const float* sa2_b   = (const float*)d_in[12];
    const float* sa3_w   = (const float*)d_in[13];
    const float* sa3_b   = (const float*)d_in[14];
    const float* weights = (const float*)d_in[15];
    const float* weights2= (const float*)d_in[16];
    const float* w_back  = (const float*)d_in[17];
    float* out = (float*)d_out;

    // workspace (same slot offsets as previous rounds; off/pcl/xbl slots now unused)
    float* ws    = (float*)d_ws;
    float* x2T   = ws;                               // CTHW_ f32
    float* stats = x2T;                              // overlay: 221,184 f32
    float* yb    = stats + 2 * 3 * THW_;             // 73,728
    float* agg0  = yb + 2 * THW_;                    // 147,456
    _Float16* partb = (_Float16*)(agg0 + RC_ * THW_);  // 1,179,648 fp16
    float* off   = ws + CTHW_;                       // 36,864 f32 (unused now)
    _Float16* xfh = (_Float16*)(off + 2 * T_ * 2 * SD_);  // CTHW_ fp16 (old xbh slot)
    _Float16* pxh = (_Float16*)((unsigned short*)xfh + 2 * CTHW_);  // old pch slot
    float* xd    = (float*)((unsigned short*)pxh + 2 * (2 * 16 * 576 * 64)); // old slot arith kept safe

    k_pre<<<THW_ / 64, 256, 0, stream>>>(x, w_dc2, w_down, x2T, xfh, xd);
    k_gs<<<(2 * 16 * 576) / 4, 256, 0, stream>>>(xfh, x2T, w_ofs_l, b_ofs_l,
                                                 w_ofs_r, b_ofs_r, pxh);
    k_stats<<<2 * 16 * 36, 256, 0, stream>>>(xfh, pxh, stats);
    k_aux<<<(2 * THW_) / 256 + (RC_ * THW_) / 256 + 32 * 9, 256, 0, stream>>>(
        stats, ca_w1, ca_w2, yb, xd, sa1_w, sa1_b, sa2_w, sa2_b,
        sa3_w, sa3_b, weights, agg0, pxh, partb);
    k_final<<<2 * 16 * 36, 256, 0, stream>>>(xfh, pxh, partb, yb, weights2,
                                             agg0, w_back, out);
}